// Round 1
// baseline (233.285 us; speedup 1.0000x reference)
//
#include <hip/hip_runtime.h>
#include <hip/hip_bf16.h>

#define HEADS 8
#define DHEAD 64
#define CDIM  512
#define BATCH 2
#define SEQ   2304      // 48*48
#define ND    512       // HEADS*DHEAD
#define M3    1536      // 3*ND

typedef unsigned short u16;
typedef unsigned int   u32;
typedef __attribute__((ext_vector_type(8))) short short8;
typedef __attribute__((ext_vector_type(4))) float f32x4;

__device__ __forceinline__ u16 f2bf(float f) {
    union { float f; u32 u; } x; x.f = f;
    u32 r = x.u + 0x7FFFu + ((x.u >> 16) & 1u);   // RNE
    return (u16)(r >> 16);
}

__device__ __forceinline__ f32x4 mfma16(short8 a, short8 b, f32x4 c) {
    return __builtin_amdgcn_mfma_f32_16x16x32_bf16(a, b, c, 0, 0, 0);
}

// ---------------- weight convert: Wq/Wk/Wv -> stacked bf16 [1536][512], Wo -> bf16 [512][512]
__global__ void convert_w(const float* __restrict__ Wq, const float* __restrict__ Wk,
                          const float* __restrict__ Wv, const float* __restrict__ Wo,
                          u16* __restrict__ Wqkv, u16* __restrict__ Wob) {
    int idx = blockIdx.x * 256 + threadIdx.x;       // grid covers 4*262144 exactly
    const int N1 = CDIM * ND;                       // 262144
    if (idx < N1)             Wqkv[idx] = f2bf(Wq[idx]);
    else if (idx < 2 * N1)    Wqkv[idx] = f2bf(Wk[idx - N1]);
    else if (idx < 3 * N1)    Wqkv[idx] = f2bf(Wv[idx - 2 * N1]);
    else                      Wob[idx - 3 * N1] = f2bf(Wo[idx - 3 * N1]);
}

// ---------------- x transpose: H [B][C][S] fp32 -> Xbf [B][S][C] bf16
__global__ void transpose_x(const float* __restrict__ H, u16* __restrict__ X) {
    __shared__ float tile[32][33];
    int st = blockIdx.x, ct = blockIdx.y, b = blockIdx.z;
    int tx = threadIdx.x, ty = threadIdx.y;         // block (32,8)
#pragma unroll
    for (int k = 0; k < 4; ++k) {
        int c = ct * 32 + ty + k * 8;
        tile[ty + k * 8][tx] = H[((size_t)b * CDIM + c) * SEQ + st * 32 + tx];
    }
    __syncthreads();
#pragma unroll
    for (int k = 0; k < 4; ++k) {
        int s = st * 32 + ty + k * 8;
        X[((size_t)b * SEQ + s) * CDIM + ct * 32 + tx] = f2bf(tile[tx][ty + k * 8]);
    }
}

// ---------------- QKV projection GEMM (NT): C[m][n] = sum_k Wqkv[m][k] * Xbf[b][n][k]
// M=1536 (nd3), N=2304 (s), K=512 (c). Epilogue scatters to Q/K [pair][s][d] and V [b][nd][s], bf16.
__global__ __launch_bounds__(256) void gemm_qkv_kernel(
        const u16* __restrict__ W,      // [1536][512] bf16
        const u16* __restrict__ X,      // [B][2304][512] bf16
        const float* __restrict__ bq, const float* __restrict__ bk, const float* __restrict__ bv,
        u16* __restrict__ Q, u16* __restrict__ K, u16* __restrict__ V) {
    __shared__ __align__(16) u16 As[128 * 72];
    __shared__ __align__(16) u16 Bs[128 * 72];
    const int n0 = blockIdx.x * 128;
    const int m0 = blockIdx.y * 128;
    const int b  = blockIdx.z;
    const int t = threadIdx.x;
    const int lane = t & 63, w = t >> 6;
    const int l16 = lane & 15, quad = lane >> 4;
    const int wm = (w >> 1) * 64, wn = (w & 1) * 64;
    const u16* Xb = X + (size_t)b * SEQ * CDIM;

    f32x4 acc[4][4] = {};

    for (int kb = 0; kb < 512; kb += 64) {
        __syncthreads();
#pragma unroll
        for (int it = 0; it < 4; ++it) {
            int i = it * 256 + t;                    // 0..1023
            int row = i >> 3, col = (i & 7) * 8;
            *(uint4*)&As[row * 72 + col] = *(const uint4*)&W [(size_t)(m0 + row) * 512 + kb + col];
            *(uint4*)&Bs[row * 72 + col] = *(const uint4*)&Xb[(size_t)(n0 + row) * 512 + kb + col];
        }
        __syncthreads();
#pragma unroll
        for (int kk = 0; kk < 2; ++kk) {
            short8 af[4], bfr[4];
#pragma unroll
            for (int i = 0; i < 4; ++i)
                af[i] = *(const short8*)&As[(wm + i * 16 + l16) * 72 + kk * 32 + quad * 8];
#pragma unroll
            for (int j = 0; j < 4; ++j)
                bfr[j] = *(const short8*)&Bs[(wn + j * 16 + l16) * 72 + kk * 32 + quad * 8];
#pragma unroll
            for (int i = 0; i < 4; ++i)
#pragma unroll
                for (int j = 0; j < 4; ++j)
                    acc[i][j] = mfma16(af[i], bfr[j], acc[i][j]);
        }
    }
    // epilogue: m<512 -> Q, <1024 -> K, else -> V(transposed [nd][s])
#pragma unroll
    for (int i = 0; i < 4; ++i) {
        int mbase = m0 + wm + i * 16 + quad * 4;
#pragma unroll
        for (int j = 0; j < 4; ++j) {
            int s = n0 + wn + j * 16 + l16;
#pragma unroll
            for (int r = 0; r < 4; ++r) {
                int m = mbase + r;
                float v = acc[i][j][r];
                if (m < 512) {
                    v += bq[m];
                    Q[((size_t)(b * 8 + (m >> 6)) * SEQ + s) * 64 + (m & 63)] = f2bf(v);
                } else if (m < 1024) {
                    int mm = m - 512; v += bk[mm];
                    K[((size_t)(b * 8 + (mm >> 6)) * SEQ + s) * 64 + (mm & 63)] = f2bf(v);
                } else {
                    int mm = m - 1024; v += bv[mm];
                    V[((size_t)(b * 512 + mm)) * SEQ + s] = f2bf(v);
                }
            }
        }
    }
}

// ---------------- flash attention: 16 pairs x 36 Q-tiles(64). K/V tiles of 64 in LDS.
__global__ __launch_bounds__(256) void attn_kernel(
        const u16* __restrict__ Q,   // [16][2304][64]
        const u16* __restrict__ K,   // [16][2304][64]
        const u16* __restrict__ Vt,  // [B][512][2304]  (row nd, col s)
        u16* __restrict__ At) {      // [B][2304][512]
    __shared__ __align__(16) u16 Qs[64 * 72];
    __shared__ __align__(16) u16 Ks[64 * 72];
    __shared__ __align__(16) u16 Vs[64 * 72];
    __shared__ __align__(16) u16 Ps[64 * 72];
    const int bx = blockIdx.x;
    const int pair = bx & 15, qt = bx >> 4;
    const int b = pair >> 3, h = pair & 7;
    const int t = threadIdx.x, lane = t & 63, w = t >> 6;
    const int l16 = lane & 15, quad = lane >> 4;
    const u16* Qg = Q  + ((size_t)pair * SEQ + qt * 64) * 64;
    const u16* Kg = K  + (size_t)pair * SEQ * 64;
    const u16* Vg = Vt + ((size_t)b * 512 + h * 64) * SEQ;

    // stage Q tile 64x64 -> padded LDS, pull A-frags to registers
#pragma unroll
    for (int it = 0; it < 2; ++it) {
        int i = it * 256 + t;                        // 0..511
        int row = i >> 3, col = (i & 7) * 8;
        *(uint4*)&Qs[row * 72 + col] = *(const uint4*)&Qg[(size_t)row * 64 + col];
    }
    __syncthreads();
    short8 qf0 = *(const short8*)&Qs[(w * 16 + l16) * 72 + quad * 8];
    short8 qf1 = *(const short8*)&Qs[(w * 16 + l16) * 72 + 32 + quad * 8];

    float m_r[4], l_r[4];
    f32x4 o[4] = {};
#pragma unroll
    for (int r = 0; r < 4; ++r) { m_r[r] = -1e30f; l_r[r] = 0.f; }
    const float scale = 0.125f;

    for (int kt = 0; kt < 36; ++kt) {
        __syncthreads();
#pragma unroll
        for (int it = 0; it < 2; ++it) {
            int i = it * 256 + t;
            int row = i >> 3, col = (i & 7) * 8;
            *(uint4*)&Ks[row * 72 + col] = *(const uint4*)&Kg[(size_t)(kt * 64 + row) * 64 + col];
            *(uint4*)&Vs[row * 72 + col] = *(const uint4*)&Vg[(size_t)row * SEQ + kt * 64 + col];
        }
        __syncthreads();
        // S = Q K^T  (rows qi = quad*4+r, cols ki = j*16+l16)
        f32x4 sacc[4] = {};
#pragma unroll
        for (int j = 0; j < 4; ++j) {
            short8 kf0 = *(const short8*)&Ks[(j * 16 + l16) * 72 + quad * 8];
            short8 kf1 = *(const short8*)&Ks[(j * 16 + l16) * 72 + 32 + quad * 8];
            sacc[j] = mfma16(qf0, kf0, sacc[j]);
            sacc[j] = mfma16(qf1, kf1, sacc[j]);
        }
        // online softmax (row stats replicated across the 16 lanes of each quad)
        float rm[4];
#pragma unroll
        for (int r = 0; r < 4; ++r)
            rm[r] = fmaxf(fmaxf(sacc[0][r], sacc[1][r]), fmaxf(sacc[2][r], sacc[3][r]));
#pragma unroll
        for (int off = 1; off <= 8; off <<= 1)
#pragma unroll
            for (int r = 0; r < 4; ++r)
                rm[r] = fmaxf(rm[r], __shfl_xor(rm[r], off));
        float p[4][4], rs[4], al[4];
#pragma unroll
        for (int r = 0; r < 4; ++r) {
            float mnew = fmaxf(m_r[r], rm[r] * scale);
            al[r] = __expf(m_r[r] - mnew);
            m_r[r] = mnew;
            rs[r] = 0.f;
#pragma unroll
            for (int j = 0; j < 4; ++j) {
                p[j][r] = __expf(sacc[j][r] * scale - mnew);
                rs[r] += p[j][r];
            }
        }
#pragma unroll
        for (int off = 1; off <= 8; off <<= 1)
#pragma unroll
            for (int r = 0; r < 4; ++r)
                rs[r] += __shfl_xor(rs[r], off);
#pragma unroll
        for (int r = 0; r < 4; ++r) l_r[r] = l_r[r] * al[r] + rs[r];
#pragma unroll
        for (int j = 0; j < 4; ++j)
#pragma unroll
            for (int r = 0; r < 4; ++r)
                o[j][r] *= al[r];
        // P: C-layout -> LDS -> A-layout (round trip)
#pragma unroll
        for (int j = 0; j < 4; ++j)
#pragma unroll
            for (int r = 0; r < 4; ++r)
                Ps[(w * 16 + quad * 4 + r) * 72 + j * 16 + l16] = f2bf(p[j][r]);
        __syncthreads();
        short8 pf0 = *(const short8*)&Ps[(w * 16 + l16) * 72 + quad * 8];
        short8 pf1 = *(const short8*)&Ps[(w * 16 + l16) * 72 + 32 + quad * 8];
#pragma unroll
        for (int j = 0; j < 4; ++j) {
            short8 vf0 = *(const short8*)&Vs[(j * 16 + l16) * 72 + quad * 8];
            short8 vf1 = *(const short8*)&Vs[(j * 16 + l16) * 72 + 32 + quad * 8];
            o[j] = mfma16(pf0, vf0, o[j]);
            o[j] = mfma16(pf1, vf1, o[j]);
        }
    }
    // epilogue -> At[b][s][h*64+d] bf16
    float inv[4];
#pragma unroll
    for (int r = 0; r < 4; ++r) inv[r] = 1.0f / l_r[r];
#pragma unroll
    for (int j = 0; j < 4; ++j)
#pragma unroll
        for (int r = 0; r < 4; ++r) {
            int s = qt * 64 + w * 16 + quad * 4 + r;
            At[((size_t)b * SEQ + s) * ND + h * 64 + j * 16 + l16] = f2bf(o[j][r] * inv[r]);
        }
}

// ---------------- output projection GEMM (NT): out[b][c][s] = sum_nd Wo[c][nd]*At[b][s][nd] + bo[c]
__global__ __launch_bounds__(256) void gemm_out_kernel(
        const u16* __restrict__ Wob,    // [512][512] bf16
        const u16* __restrict__ At,     // [B][2304][512] bf16
        const float* __restrict__ bo,
        float* __restrict__ out) {      // [B][512][2304] fp32
    __shared__ __align__(16) u16 As[128 * 72];
    __shared__ __align__(16) u16 Bs[128 * 72];
    const int n0 = blockIdx.x * 128;
    const int m0 = blockIdx.y * 128;
    const int b  = blockIdx.z;
    const int t = threadIdx.x;
    const int lane = t & 63, w = t >> 6;
    const int l16 = lane & 15, quad = lane >> 4;
    const int wm = (w >> 1) * 64, wn = (w & 1) * 64;
    const u16* Ab = At + (size_t)b * SEQ * ND;

    f32x4 acc[4][4] = {};

    for (int kb = 0; kb < 512; kb += 64) {
        __syncthreads();
#pragma unroll
        for (int it = 0; it < 4; ++it) {
            int i = it * 256 + t;
            int row = i >> 3, col = (i & 7) * 8;
            *(uint4*)&As[row * 72 + col] = *(const uint4*)&Wob[(size_t)(m0 + row) * 512 + kb + col];
            *(uint4*)&Bs[row * 72 + col] = *(const uint4*)&Ab [(size_t)(n0 + row) * 512 + kb + col];
        }
        __syncthreads();
#pragma unroll
        for (int kk = 0; kk < 2; ++kk) {
            short8 af[4], bfr[4];
#pragma unroll
            for (int i = 0; i < 4; ++i)
                af[i] = *(const short8*)&As[(wm + i * 16 + l16) * 72 + kk * 32 + quad * 8];
#pragma unroll
            for (int j = 0; j < 4; ++j)
                bfr[j] = *(const short8*)&Bs[(wn + j * 16 + l16) * 72 + kk * 32 + quad * 8];
#pragma unroll
            for (int i = 0; i < 4; ++i)
#pragma unroll
                for (int j = 0; j < 4; ++j)
                    acc[i][j] = mfma16(af[i], bfr[j], acc[i][j]);
        }
    }
#pragma unroll
    for (int i = 0; i < 4; ++i) {
        int cbase = m0 + wm + i * 16 + quad * 4;
#pragma unroll
        for (int j = 0; j < 4; ++j) {
            int s = n0 + wn + j * 16 + l16;
#pragma unroll
            for (int r = 0; r < 4; ++r) {
                int c = cbase + r;
                out[((size_t)(b * 512 + c)) * SEQ + s] = acc[i][j][r] + bo[c];
            }
        }
    }
}

extern "C" void kernel_launch(void* const* d_in, const int* in_sizes, int n_in,
                              void* d_out, int out_size, void* d_ws, size_t ws_size,
                              hipStream_t stream) {
    const float* H  = (const float*)d_in[0];
    const float* Wq = (const float*)d_in[1];
    const float* bq = (const float*)d_in[2];
    const float* Wk = (const float*)d_in[3];
    const float* bk = (const float*)d_in[4];
    const float* Wv = (const float*)d_in[5];
    const float* bv = (const float*)d_in[6];
    const float* Wo = (const float*)d_in[7];
    const float* bo = (const float*)d_in[8];
    float* out = (float*)d_out;

    u16* ws   = (u16*)d_ws;
    u16* Wqkv = ws;                                  // 1536*512
    u16* Wob  = Wqkv + 1536 * 512;                   // 512*512
    u16* Xbf  = Wob  + 512 * 512;                    // 2*2304*512
    u16* Qb   = Xbf  + 2 * SEQ * CDIM;               // 2*8*2304*64
    u16* Kb   = Qb   + 2 * SEQ * ND;
    u16* Vb   = Kb   + 2 * SEQ * ND;
    u16* At   = Vb   + 2 * SEQ * ND;

    convert_w<<<4096, 256, 0, stream>>>(Wq, Wk, Wv, Wo, Wqkv, Wob);
    transpose_x<<<dim3(72, 16, 2), dim3(32, 8), 0, stream>>>(H, Xbf);
    gemm_qkv_kernel<<<dim3(18, 12, 2), 256, 0, stream>>>(Wqkv, Xbf, bq, bk, bv, Qb, Kb, Vb);
    attn_kernel<<<576, 256, 0, stream>>>(Qb, Kb, Vb, At);
    gemm_out_kernel<<<dim3(18, 4, 2), 256, 0, stream>>>(Wob, At, bo, out);
}

// Round 2
// 162.428 us; speedup vs baseline: 1.4362x; 1.4362x over previous
//
#include <hip/hip_runtime.h>
#include <hip/hip_bf16.h>

#define HEADS 8
#define DHEAD 64
#define CDIM  512
#define SEQ   2304      // 48*48
#define ND    512       // HEADS*DHEAD

typedef unsigned short u16;
typedef unsigned int   u32;
typedef __attribute__((ext_vector_type(8))) short short8;
typedef __attribute__((ext_vector_type(4))) float f32x4;

#define QSCALE 0.18033688011112043f   // 0.125 * log2(e): folded into Q so softmax is exp2

__device__ __forceinline__ u16 f2bf(float f) {
    union { float f; u32 u; } x; x.f = f;
    u32 r = x.u + 0x7FFFu + ((x.u >> 16) & 1u);   // RNE
    return (u16)(r >> 16);
}
__device__ __forceinline__ float bf2f(u16 v) {
    union { u32 u; float f; } x; x.u = ((u32)v) << 16; return x.f;
}
__device__ __forceinline__ f32x4 mfma16(short8 a, short8 b, f32x4 c) {
    return __builtin_amdgcn_mfma_f32_16x16x32_bf16(a, b, c, 0, 0, 0);
}
// ki -> LDS slot permutation so post-softmax P is already in B-frag order for PV.
// slot = keep bit5..., move bit2(T)->bit4, bits[4:3](Qd)->bits[3:2], keep bits[1:0]
__device__ __forceinline__ int kperm(int r) {
    return (r & ~0x1C) | ((r & 4) << 2) | ((r & 0x18) >> 1);
}

// ---------------- weight convert: Wq/Wk/Wv -> stacked bf16 [1536][512], Wo -> bf16
__global__ void convert_w(const float* __restrict__ Wq, const float* __restrict__ Wk,
                          const float* __restrict__ Wv, const float* __restrict__ Wo,
                          u16* __restrict__ Wqkv, u16* __restrict__ Wob) {
    int idx = blockIdx.x * 256 + threadIdx.x;
    const int N1 = CDIM * ND;
    if (idx < N1)             Wqkv[idx] = f2bf(Wq[idx]);
    else if (idx < 2 * N1)    Wqkv[idx] = f2bf(Wk[idx - N1]);
    else if (idx < 3 * N1)    Wqkv[idx] = f2bf(Wv[idx - 2 * N1]);
    else                      Wob[idx - 3 * N1] = f2bf(Wo[idx - 3 * N1]);
}

// ---------------- x transpose: H [B][C][S] fp32 -> Xbf [B][S][C] bf16
__global__ void transpose_x(const float* __restrict__ H, u16* __restrict__ X) {
    __shared__ float tile[32][33];
    int st = blockIdx.x, ct = blockIdx.y, b = blockIdx.z;
    int tx = threadIdx.x, ty = threadIdx.y;
#pragma unroll
    for (int k = 0; k < 4; ++k) {
        int c = ct * 32 + ty + k * 8;
        tile[ty + k * 8][tx] = H[((size_t)b * CDIM + c) * SEQ + st * 32 + tx];
    }
    __syncthreads();
#pragma unroll
    for (int k = 0; k < 4; ++k) {
        int s = st * 32 + ty + k * 8;
        X[((size_t)b * SEQ + s) * CDIM + ct * 32 + tx] = f2bf(tile[tx][ty + k * 8]);
    }
}

// ---------------- QKV projection GEMM (NT), epilogue: Q/K via coalescing LDS bounce, V direct
__global__ __launch_bounds__(256) void gemm_qkv_kernel(
        const u16* __restrict__ W, const u16* __restrict__ X,
        const float* __restrict__ bq, const float* __restrict__ bk, const float* __restrict__ bv,
        u16* __restrict__ Q, u16* __restrict__ K, u16* __restrict__ V) {
    __shared__ __align__(16) u16 smem[2 * 128 * 72];
    u16* As = smem;
    u16* Bs = smem + 128 * 72;
    u16* Ct = smem;                       // reused after the K-loop (128 x 136 <= 18432)
    const int n0 = blockIdx.x * 128;
    const int m0 = blockIdx.y * 128;
    const int b  = blockIdx.z;
    const int t = threadIdx.x;
    const int lane = t & 63, w = t >> 6;
    const int l16 = lane & 15, quad = lane >> 4;
    const int wm = (w >> 1) * 64, wn = (w & 1) * 64;
    const u16* Xb = X + (size_t)b * SEQ * CDIM;

    f32x4 acc[4][4] = {};

    for (int kb = 0; kb < 512; kb += 64) {
        __syncthreads();
#pragma unroll
        for (int it = 0; it < 4; ++it) {
            int i = it * 256 + t;
            int row = i >> 3, col = (i & 7) * 8;
            *(uint4*)&As[row * 72 + col] = *(const uint4*)&W [(size_t)(m0 + row) * 512 + kb + col];
            *(uint4*)&Bs[row * 72 + col] = *(const uint4*)&Xb[(size_t)(n0 + row) * 512 + kb + col];
        }
        __syncthreads();
#pragma unroll
        for (int kk = 0; kk < 2; ++kk) {
            short8 af[4], bfr[4];
#pragma unroll
            for (int i = 0; i < 4; ++i)
                af[i] = *(const short8*)&As[(wm + i * 16 + l16) * 72 + kk * 32 + quad * 8];
#pragma unroll
            for (int j = 0; j < 4; ++j)
                bfr[j] = *(const short8*)&Bs[(wn + j * 16 + l16) * 72 + kk * 32 + quad * 8];
#pragma unroll
            for (int i = 0; i < 4; ++i)
#pragma unroll
                for (int j = 0; j < 4; ++j)
                    acc[i][j] = mfma16(af[i], bfr[j], acc[i][j]);
        }
    }

    if (m0 < 1024) {
        // Q or K block: bounce through LDS for fully coalesced 16B stores
        const bool isQ = (m0 < 512);
        const float* bias = isQ ? bq : bk;
        const float sc = isQ ? QSCALE : 1.0f;
        const int mq = isQ ? m0 : m0 - 512;
        __syncthreads();
#pragma unroll
        for (int i = 0; i < 4; ++i) {
            int mloc = wm + i * 16 + quad * 4;
#pragma unroll
            for (int j = 0; j < 4; ++j) {
                int srow = wn + j * 16 + l16;
                ushort4 pk;
                pk.x = f2bf((acc[i][j][0] + bias[mq + mloc + 0]) * sc);
                pk.y = f2bf((acc[i][j][1] + bias[mq + mloc + 1]) * sc);
                pk.z = f2bf((acc[i][j][2] + bias[mq + mloc + 2]) * sc);
                pk.w = f2bf((acc[i][j][3] + bias[mq + mloc + 3]) * sc);
                *(ushort4*)&Ct[srow * 136 + mloc] = pk;
            }
        }
        __syncthreads();
        u16* dst = isQ ? Q : K;
#pragma unroll
        for (int it = 0; it < 8; ++it) {
            int v = it * 256 + t;
            int srow = v >> 4, c16 = v & 15;
            int head = (mq >> 6) + (c16 >> 3);
            int d = (c16 & 7) * 8;
            uint4 val = *(const uint4*)&Ct[srow * 136 + c16 * 8];
            *(uint4*)&dst[(((size_t)(b * 8 + head)) * SEQ + n0 + srow) * 64 + d] = val;
        }
    } else {
        // V block -> [b][nd][s] (16 lanes give 32B-contiguous chunks)
#pragma unroll
        for (int i = 0; i < 4; ++i) {
            int mbase = m0 - 1024 + wm + i * 16 + quad * 4;
#pragma unroll
            for (int j = 0; j < 4; ++j) {
                int s = n0 + wn + j * 16 + l16;
#pragma unroll
                for (int r = 0; r < 4; ++r) {
                    int mm = mbase + r;
                    V[((size_t)(b * 512 + mm)) * SEQ + s] = f2bf(acc[i][j][r] + bv[mm]);
                }
            }
        }
    }
}

// ---------------- flash attention partial (split-K x4): S^T = K Q^T, O^T = V^T P^T
__global__ __launch_bounds__(256) void attn_partial(
        const u16* __restrict__ Q,    // [16][2304][64] (pre-scaled by QSCALE)
        const u16* __restrict__ K,    // [16][2304][64]
        const u16* __restrict__ Vt,   // [B][512][2304]
        u16* __restrict__ Opart,      // [4*16][2304][64] chunk-normalized bf16
        float* __restrict__ Mpart,    // [4*16][2304]
        float* __restrict__ Lpart) {  // [4*16][2304]
    __shared__ __align__(16) u16 Ks[64 * 72];
    __shared__ __align__(16) u16 Vs[64 * 72];
    const int pair = blockIdx.x & 15, qt = blockIdx.x >> 4;
    const int c = blockIdx.y;
    const int b = pair >> 3, h = pair & 7;
    const int t = threadIdx.x, lane = t & 63, w = t >> 6;
    const int l16 = lane & 15, quad = lane >> 4;

    // Q fragments straight from global (one-time): B-frag n=l16(qi), k=d
    const u16* Qg = Q + ((size_t)pair * SEQ + qt * 64) * 64;
    short8 qf0 = *(const short8*)&Qg[(size_t)(w * 16 + l16) * 64 + quad * 8];
    short8 qf1 = *(const short8*)&Qg[(size_t)(w * 16 + l16) * 64 + 32 + quad * 8];

    const u16* Kg = K  + ((size_t)pair * SEQ + c * 576) * 64;
    const u16* Vg = Vt + ((size_t)(b * 512 + h * 64)) * SEQ + c * 576;

    float mrow = -1e30f, lrow = 0.f;
    f32x4 o[4] = {};

    for (int kt = 0; kt < 9; ++kt) {
        __syncthreads();
#pragma unroll
        for (int it = 0; it < 2; ++it) {
            int v = it * 256 + t;
            int row = v >> 3, col = (v & 7) * 8;
            *(uint4*)&Ks[kperm(row) * 72 + col] = *(const uint4*)&Kg[(size_t)(kt * 64 + row) * 64 + col];
            *(uint4*)&Vs[row * 72 + col]        = *(const uint4*)&Vg[(size_t)row * SEQ + kt * 64 + col];
        }
        __syncthreads();
        // S^T: rows = ki (permuted), cols = qi
        f32x4 sacc[4] = {};
#pragma unroll
        for (int j = 0; j < 4; ++j) {
            short8 kf0 = *(const short8*)&Ks[(j * 16 + l16) * 72 + quad * 8];
            short8 kf1 = *(const short8*)&Ks[(j * 16 + l16) * 72 + 32 + quad * 8];
            sacc[j] = mfma16(kf0, qf0, sacc[j]);
            sacc[j] = mfma16(kf1, qf1, sacc[j]);
        }
        // online softmax: each lane owns ONE query (l16) and 16 key scores
        float rm = sacc[0][0];
#pragma unroll
        for (int j = 0; j < 4; ++j)
#pragma unroll
            for (int r = 0; r < 4; ++r) rm = fmaxf(rm, sacc[j][r]);
        rm = fmaxf(rm, __shfl_xor(rm, 16));
        rm = fmaxf(rm, __shfl_xor(rm, 32));
        float mnew = fmaxf(mrow, rm);
        float al = exp2f(mrow - mnew);
        mrow = mnew;
        float p[4][4];
        float rs = 0.f;
#pragma unroll
        for (int j = 0; j < 4; ++j)
#pragma unroll
            for (int r = 0; r < 4; ++r) {
                p[j][r] = exp2f(sacc[j][r] - mnew);
                rs += p[j][r];
            }
        rs += __shfl_xor(rs, 16);
        rs += __shfl_xor(rs, 32);
        lrow = lrow * al + rs;
#pragma unroll
        for (int i = 0; i < 4; ++i)
#pragma unroll
            for (int r = 0; r < 4; ++r) o[i][r] *= al;
        // PV: P is already in B-frag order thanks to kperm (k = quad*8 + (j&1)*4 + r)
#pragma unroll
        for (int g = 0; g < 2; ++g) {
            short8 pf;
            pf[0] = (short)f2bf(p[2 * g][0]);
            pf[1] = (short)f2bf(p[2 * g][1]);
            pf[2] = (short)f2bf(p[2 * g][2]);
            pf[3] = (short)f2bf(p[2 * g][3]);
            pf[4] = (short)f2bf(p[2 * g + 1][0]);
            pf[5] = (short)f2bf(p[2 * g + 1][1]);
            pf[6] = (short)f2bf(p[2 * g + 1][2]);
            pf[7] = (short)f2bf(p[2 * g + 1][3]);
#pragma unroll
            for (int i = 0; i < 4; ++i) {
                short8 vf = *(const short8*)&Vs[(i * 16 + l16) * 72 + g * 32 + quad * 8];
                o[i] = mfma16(vf, pf, o[i]);
            }
        }
    }
    // epilogue: normalize by chunk l, bounce O^T -> [s][d] rows through LDS, coalesced store
    float inv = 1.0f / lrow;
    __syncthreads();
#pragma unroll
    for (int i = 0; i < 4; ++i) {
        ushort4 pk;
        pk.x = f2bf(o[i][0] * inv);
        pk.y = f2bf(o[i][1] * inv);
        pk.z = f2bf(o[i][2] * inv);
        pk.w = f2bf(o[i][3] * inv);
        *(ushort4*)&Ks[(w * 16 + l16) * 72 + i * 16 + quad * 4] = pk;
    }
    if (quad == 0) {
        Mpart[(size_t)(c * 16 + pair) * SEQ + qt * 64 + w * 16 + l16] = mrow;
        Lpart[(size_t)(c * 16 + pair) * SEQ + qt * 64 + w * 16 + l16] = lrow;
    }
    __syncthreads();
#pragma unroll
    for (int it = 0; it < 2; ++it) {
        int v = it * 256 + t;
        int row = v >> 3, col = (v & 7) * 8;
        *(uint4*)&Opart[(((size_t)(c * 16 + pair)) * SEQ + qt * 64 + row) * 64 + col] =
            *(const uint4*)&Ks[row * 72 + col];
    }
}

// ---------------- combine split-K partials -> At [B][2304][512] bf16
__global__ __launch_bounds__(256) void attn_combine(
        const u16* __restrict__ Opart, const float* __restrict__ Mpart,
        const float* __restrict__ Lpart, u16* __restrict__ At) {
    const int bid = blockIdx.x;
    const int pair = bid / 144, sb = bid % 144;
    const int tid = threadIdx.x;
    const int rl = tid >> 4, dg = tid & 15;
    const int s = sb * 16 + rl;
    const int b = pair >> 3, h = pair & 7;
    float mc[4], M = -1e30f;
#pragma unroll
    for (int c = 0; c < 4; ++c) {
        mc[c] = Mpart[(size_t)(c * 16 + pair) * SEQ + s];
        M = fmaxf(M, mc[c]);
    }
    float wgt[4], L = 0.f;
#pragma unroll
    for (int c = 0; c < 4; ++c) {
        wgt[c] = Lpart[(size_t)(c * 16 + pair) * SEQ + s] * exp2f(mc[c] - M);
        L += wgt[c];
    }
    float invL = 1.0f / L;
    float acc[4] = {0.f, 0.f, 0.f, 0.f};
#pragma unroll
    for (int c = 0; c < 4; ++c) {
        ushort4 v = *(const ushort4*)&Opart[((size_t)(c * 16 + pair) * SEQ + s) * 64 + dg * 4];
        acc[0] += wgt[c] * bf2f(v.x);
        acc[1] += wgt[c] * bf2f(v.y);
        acc[2] += wgt[c] * bf2f(v.z);
        acc[3] += wgt[c] * bf2f(v.w);
    }
    ushort4 outv;
    outv.x = f2bf(acc[0] * invL);
    outv.y = f2bf(acc[1] * invL);
    outv.z = f2bf(acc[2] * invL);
    outv.w = f2bf(acc[3] * invL);
    *(ushort4*)&At[((size_t)b * SEQ + s) * ND + h * 64 + dg * 4] = outv;
}

// ---------------- output projection GEMM (NT): out[b][c][s] = Wo At^T + bo
__global__ __launch_bounds__(256) void gemm_out_kernel(
        const u16* __restrict__ Wob, const u16* __restrict__ At,
        const float* __restrict__ bo, float* __restrict__ out) {
    __shared__ __align__(16) u16 As[128 * 72];
    __shared__ __align__(16) u16 Bs[128 * 72];
    const int n0 = blockIdx.x * 128;
    const int m0 = blockIdx.y * 128;
    const int b  = blockIdx.z;
    const int t = threadIdx.x;
    const int lane = t & 63, w = t >> 6;
    const int l16 = lane & 15, quad = lane >> 4;
    const int wm = (w >> 1) * 64, wn = (w & 1) * 64;
    const u16* Ab = At + (size_t)b * SEQ * ND;

    f32x4 acc[4][4] = {};

    for (int kb = 0; kb < 512; kb += 64) {
        __syncthreads();
#pragma unroll
        for (int it = 0; it < 4; ++it) {
            int i = it * 256 + t;
            int row = i >> 3, col = (i & 7) * 8;
            *(uint4*)&As[row * 72 + col] = *(const uint4*)&Wob[(size_t)(m0 + row) * 512 + kb + col];
            *(uint4*)&Bs[row * 72 + col] = *(const uint4*)&Ab [(size_t)(n0 + row) * 512 + kb + col];
        }
        __syncthreads();
#pragma unroll
        for (int kk = 0; kk < 2; ++kk) {
            short8 af[4], bfr[4];
#pragma unroll
            for (int i = 0; i < 4; ++i)
                af[i] = *(const short8*)&As[(wm + i * 16 + l16) * 72 + kk * 32 + quad * 8];
#pragma unroll
            for (int j = 0; j < 4; ++j)
                bfr[j] = *(const short8*)&Bs[(wn + j * 16 + l16) * 72 + kk * 32 + quad * 8];
#pragma unroll
            for (int i = 0; i < 4; ++i)
#pragma unroll
                for (int j = 0; j < 4; ++j)
                    acc[i][j] = mfma16(af[i], bfr[j], acc[i][j]);
        }
    }
#pragma unroll
    for (int i = 0; i < 4; ++i) {
        int cbase = m0 + wm + i * 16 + quad * 4;
#pragma unroll
        for (int j = 0; j < 4; ++j) {
            int s = n0 + wn + j * 16 + l16;
#pragma unroll
            for (int r = 0; r < 4; ++r) {
                int cc = cbase + r;
                out[((size_t)(b * 512 + cc)) * SEQ + s] = acc[i][j][r] + bo[cc];
            }
        }
    }
}

extern "C" void kernel_launch(void* const* d_in, const int* in_sizes, int n_in,
                              void* d_out, int out_size, void* d_ws, size_t ws_size,
                              hipStream_t stream) {
    const float* H  = (const float*)d_in[0];
    const float* Wq = (const float*)d_in[1];
    const float* bq = (const float*)d_in[2];
    const float* Wk = (const float*)d_in[3];
    const float* bk = (const float*)d_in[4];
    const float* Wv = (const float*)d_in[5];
    const float* bv = (const float*)d_in[6];
    const float* Wo = (const float*)d_in[7];
    const float* bo = (const float*)d_in[8];
    float* out = (float*)d_out;

    u16* ws    = (u16*)d_ws;
    u16* Wqkv  = ws;                                  // 1536*512
    u16* Wob   = Wqkv  + 1536 * 512;                  // 512*512
    u16* Xbf   = Wob   + 512 * 512;                   // 2*2304*512
    u16* Qb    = Xbf   + 2 * SEQ * CDIM;              // 16*2304*64
    u16* Kb    = Qb    + 2 * SEQ * ND;
    u16* Vb    = Kb    + 2 * SEQ * ND;
    u16* At    = Vb    + 2 * SEQ * ND;
    u16* Opart = At    + 2 * SEQ * ND;                // 64*2304*64
    float* Mpart = (float*)(Opart + 4 * 16 * SEQ * 64);
    float* Lpart = Mpart + 4 * 16 * SEQ;

    convert_w<<<4096, 256, 0, stream>>>(Wq, Wk, Wv, Wo, Wqkv, Wob);
    transpose_x<<<dim3(72, 16, 2), dim3(32, 8), 0, stream>>>(H, Xbf);
    gemm_qkv_kernel<<<dim3(18, 12, 2), 256, 0, stream>>>(Wqkv, Xbf, bq, bk, bv, Qb, Kb, Vb);
    attn_partial<<<dim3(576, 4), 256, 0, stream>>>(Qb, Kb, Vb, Opart, Mpart, Lpart);
    attn_combine<<<2304, 256, 0, stream>>>(Opart, Mpart, Lpart, At);
    gemm_out_kernel<<<dim3(18, 4, 2), 256, 0, stream>>>(Wob, At, bo, out);
}

// Round 3
// 158.478 us; speedup vs baseline: 1.4720x; 1.0249x over previous
//
#include <hip/hip_runtime.h>
#include <hip/hip_bf16.h>

#define HEADS 8
#define DHEAD 64
#define CDIM  512
#define SEQ   2304      // 48*48
#define ND    512       // HEADS*DHEAD

typedef unsigned short u16;
typedef unsigned int   u32;
typedef __attribute__((ext_vector_type(8))) short short8;
typedef __attribute__((ext_vector_type(4))) float f32x4;

#define QSCALE 0.18033688011112043f   // 0.125 * log2(e): folded into Q so softmax is exp2

__device__ __forceinline__ u16 f2bf(float f) {
    union { float f; u32 u; } x; x.f = f;
    u32 r = x.u + 0x7FFFu + ((x.u >> 16) & 1u);   // RNE
    return (u16)(r >> 16);
}
__device__ __forceinline__ float bf2f(u16 v) {
    union { u32 u; float f; } x; x.u = ((u32)v) << 16; return x.f;
}
// pack two f32 -> two bf16 in one u32 (round-half-up via +0x8000, then v_perm byte-select)
__device__ __forceinline__ u32 pkbf(float a, float b) {
    union { float f; u32 u; } x, y; x.f = a; y.f = b;
    return __builtin_amdgcn_perm(y.u + 0x8000u, x.u + 0x8000u, 0x07060302u);
}
__device__ __forceinline__ f32x4 mfma16(short8 a, short8 b, f32x4 c) {
    return __builtin_amdgcn_mfma_f32_16x16x32_bf16(a, b, c, 0, 0, 0);
}
// async 16B global->LDS (wave-uniform base + lane*16 dest). gfx9: low 32 bits of a
// flat LDS address ARE the LDS offset, so truncation yields the AS(3) pointer.
__device__ __forceinline__ void cp16(const void* g, void* l) {
    __builtin_amdgcn_global_load_lds(
        (const __attribute__((address_space(1))) u32*)(uintptr_t)g,
        (__attribute__((address_space(3))) u32*)(u32)(uintptr_t)l,
        16, 0, 0);
}
// LDS K-slot r holds source K row kperm_inv(r), so post-softmax P sits in PV B-frag order.
__device__ __forceinline__ int kperm_inv(int r) {
    return (r & ~0x1C) | ((r & 0x0C) << 1) | ((r & 0x10) >> 2);
}

// ---------------- fused: weight convert + x transpose
__global__ void prep_kernel(const float* __restrict__ H,
                            const float* __restrict__ Wq, const float* __restrict__ Wk,
                            const float* __restrict__ Wv, const float* __restrict__ Wo,
                            u16* __restrict__ Wqkv, u16* __restrict__ Wob,
                            u16* __restrict__ X) {
    __shared__ float tile[32][33];
    const int t = threadIdx.x;
    const int bx = blockIdx.x;
    if (bx < 4096) {
        int idx = bx * 256 + t;
        const int N1 = CDIM * ND;
        if (idx < N1)             Wqkv[idx] = f2bf(Wq[idx]);
        else if (idx < 2 * N1)    Wqkv[idx] = f2bf(Wk[idx - N1]);
        else if (idx < 3 * N1)    Wqkv[idx] = f2bf(Wv[idx - 2 * N1]);
        else                      Wob[idx - 3 * N1] = f2bf(Wo[idx - 3 * N1]);
    } else {
        int bb = bx - 4096;                       // 0..2303
        int st = bb % 72, ct = (bb / 72) % 16, b = bb / (72 * 16);
        int tx = t & 31, ty = t >> 5;
#pragma unroll
        for (int k = 0; k < 4; ++k) {
            int c = ct * 32 + ty + k * 8;
            tile[ty + k * 8][tx] = H[((size_t)b * CDIM + c) * SEQ + st * 32 + tx];
        }
        __syncthreads();
#pragma unroll
        for (int k = 0; k < 4; ++k) {
            int s = st * 32 + ty + k * 8;
            X[((size_t)b * SEQ + s) * CDIM + ct * 32 + tx] = f2bf(tile[tx][ty + k * 8]);
        }
    }
}

// ---------------- QKV projection GEMM (NT), async staging, direct epilogue stores
__global__ __launch_bounds__(256) void gemm_qkv_kernel(
        const u16* __restrict__ W, const u16* __restrict__ X,
        const float* __restrict__ bq, const float* __restrict__ bk, const float* __restrict__ bv,
        u16* __restrict__ Q, u16* __restrict__ K, u16* __restrict__ V) {
    __shared__ __align__(16) u16 As[128 * 64];
    __shared__ __align__(16) u16 Bs[128 * 64];
    const int n0 = blockIdx.x * 128;
    const int m0 = blockIdx.y * 128;
    const int b  = blockIdx.z;
    const int t = threadIdx.x;
    const int lane = t & 63, w = t >> 6;
    const int l16 = lane & 15, quad = lane >> 4;
    const int wm = (w >> 1) * 64, wn = (w & 1) * 64;
    const int srow = t >> 3, scol = (t & 7) * 8;
    const u16* Xb = X + (size_t)b * SEQ * CDIM;

    f32x4 acc[4][4] = {};

    for (int kb = 0; kb < 512; kb += 64) {
        __syncthreads();
#pragma unroll
        for (int it = 0; it < 4; ++it) {
            int r2 = it * 32 + srow;
            cp16(&W [(size_t)(m0 + r2) * 512 + kb + scol], &As[r2 * 64 + scol]);
            cp16(&Xb[(size_t)(n0 + r2) * 512 + kb + scol], &Bs[r2 * 64 + scol]);
        }
        __syncthreads();
#pragma unroll
        for (int kk = 0; kk < 2; ++kk) {
            short8 af[4], bfr[4];
#pragma unroll
            for (int i = 0; i < 4; ++i)
                af[i] = *(const short8*)&As[(wm + i * 16 + l16) * 64 + kk * 32 + quad * 8];
#pragma unroll
            for (int j = 0; j < 4; ++j)
                bfr[j] = *(const short8*)&Bs[(wn + j * 16 + l16) * 64 + kk * 32 + quad * 8];
#pragma unroll
            for (int i = 0; i < 4; ++i)
#pragma unroll
                for (int j = 0; j < 4; ++j)
                    acc[i][j] = mfma16(af[i], bfr[j], acc[i][j]);
        }
    }

    if (m0 < 1024) {
        const bool isQ = (m0 < 512);
        const float* bias = isQ ? bq : bk;
        const float sc = isQ ? QSCALE : 1.0f;
        const int mq = isQ ? m0 : m0 - 512;
        u16* dst = isQ ? Q : K;
#pragma unroll
        for (int j = 0; j < 4; ++j) {
            int s = n0 + wn + j * 16 + l16;
#pragma unroll
            for (int i = 0; i < 4; ++i) {
                int mm = mq + wm + i * 16 + quad * 4;
                uint2 val;
                val.x = pkbf((acc[i][j][0] + bias[mm + 0]) * sc, (acc[i][j][1] + bias[mm + 1]) * sc);
                val.y = pkbf((acc[i][j][2] + bias[mm + 2]) * sc, (acc[i][j][3] + bias[mm + 3]) * sc);
                *(uint2*)&dst[(((size_t)(b * 8 + (mm >> 6))) * SEQ + s) * 64 + (mm & 63)] = val;
            }
        }
    } else {
#pragma unroll
        for (int j = 0; j < 4; ++j) {
            int s = n0 + wn + j * 16 + l16;
#pragma unroll
            for (int i = 0; i < 4; ++i) {
                int mbase = m0 - 1024 + wm + i * 16 + quad * 4;
#pragma unroll
                for (int r = 0; r < 4; ++r) {
                    int mm = mbase + r;
                    V[((size_t)(b * 512 + mm)) * SEQ + s] = f2bf(acc[i][j][r] + bv[mm]);
                }
            }
        }
    }
}

// ---------------- flash attention partial (split-K x4), fixed-max softmax
__global__ __launch_bounds__(256) void attn_partial(
        const u16* __restrict__ Q,    // [16][2304][64] (pre-scaled by QSCALE)
        const u16* __restrict__ K,    // [16][2304][64]
        const u16* __restrict__ Vt,   // [B][512][2304]
        u16* __restrict__ Opart,      // [4*16][2304][64] chunk-normalized bf16
        float* __restrict__ Lpart) {  // [4*16][2304]
    __shared__ __align__(16) u16 sm[2 * 64 * 64];   // Ks | Vs (unpadded for async cp)
    u16* Ks = sm;
    u16* Vs = sm + 64 * 64;
    const int pair = blockIdx.x & 15, qt = blockIdx.x >> 4;
    const int c = blockIdx.y;
    const int b = pair >> 3, h = pair & 7;
    const int t = threadIdx.x, lane = t & 63, w = t >> 6;
    const int l16 = lane & 15, quad = lane >> 4;
    const int srow = t >> 3, scol = (t & 7) * 8;
    const int kinv0 = kperm_inv(srow), kinv1 = kperm_inv(32 + srow);

    const u16* Qg = Q + ((size_t)pair * SEQ + qt * 64) * 64;
    short8 qf0 = *(const short8*)&Qg[(size_t)(w * 16 + l16) * 64 + quad * 8];
    short8 qf1 = *(const short8*)&Qg[(size_t)(w * 16 + l16) * 64 + 32 + quad * 8];

    const u16* Kg = K  + ((size_t)pair * SEQ + c * 576) * 64;
    const u16* Vg = Vt + ((size_t)(b * 512 + h * 64)) * SEQ + c * 576;

    f32x4 lacc = {0.f, 0.f, 0.f, 0.f};
    f32x4 o[4] = {};

    for (int kt = 0; kt < 9; ++kt) {
        __syncthreads();
        cp16(&Kg[(size_t)(kt * 64 + kinv0) * 64 + scol], &Ks[srow * 64 + scol]);
        cp16(&Kg[(size_t)(kt * 64 + kinv1) * 64 + scol], &Ks[(32 + srow) * 64 + scol]);
        cp16(&Vg[(size_t)srow * SEQ + kt * 64 + scol],        &Vs[srow * 64 + scol]);
        cp16(&Vg[(size_t)(32 + srow) * SEQ + kt * 64 + scol], &Vs[(32 + srow) * 64 + scol]);
        __syncthreads();
        // S^T = K Q^T : rows = ki (kperm'd), cols = qi (lane owns one q = l16)
        f32x4 sacc[4] = {};
#pragma unroll
        for (int j = 0; j < 4; ++j) {
            short8 kf0 = *(const short8*)&Ks[(j * 16 + l16) * 64 + quad * 8];
            short8 kf1 = *(const short8*)&Ks[(j * 16 + l16) * 64 + 32 + quad * 8];
            sacc[j] = mfma16(kf0, qf0, sacc[j]);
            sacc[j] = mfma16(kf1, qf1, sacc[j]);
        }
        // fixed-max softmax: p = exp2(s), accumulate l per-lane
        float p[4][4];
#pragma unroll
        for (int j = 0; j < 4; ++j)
#pragma unroll
            for (int r = 0; r < 4; ++r) {
                p[j][r] = __builtin_amdgcn_exp2f(sacc[j][r]);
                lacc[j] += p[j][r];
            }
        // PV: P already in B-frag order thanks to kperm
#pragma unroll
        for (int g = 0; g < 2; ++g) {
            short8 pf;
            u32* pw = (u32*)&pf;
            pw[0] = pkbf(p[2 * g][0], p[2 * g][1]);
            pw[1] = pkbf(p[2 * g][2], p[2 * g][3]);
            pw[2] = pkbf(p[2 * g + 1][0], p[2 * g + 1][1]);
            pw[3] = pkbf(p[2 * g + 1][2], p[2 * g + 1][3]);
#pragma unroll
            for (int i = 0; i < 4; ++i) {
                short8 vf = *(const short8*)&Vs[(i * 16 + l16) * 64 + g * 32 + quad * 8];
                o[i] = mfma16(vf, pf, o[i]);
            }
        }
    }
    // reduce l across quads (lane's q = l16)
    float lrow = lacc[0] + lacc[1] + lacc[2] + lacc[3];
    lrow += __shfl_xor(lrow, 16);
    lrow += __shfl_xor(lrow, 32);
    float inv = 1.0f / lrow;
    // bounce O^T -> [s][d] rows through LDS (stride 72 over the combined buffer), coalesced store
    __syncthreads();
#pragma unroll
    for (int i = 0; i < 4; ++i) {
        uint2 pk;
        pk.x = pkbf(o[i][0] * inv, o[i][1] * inv);
        pk.y = pkbf(o[i][2] * inv, o[i][3] * inv);
        *(uint2*)&sm[(w * 16 + l16) * 72 + i * 16 + quad * 4] = pk;
    }
    if (quad == 0)
        Lpart[(size_t)(c * 16 + pair) * SEQ + qt * 64 + w * 16 + l16] = lrow;
    __syncthreads();
#pragma unroll
    for (int it = 0; it < 2; ++it) {
        int v = it * 256 + t;
        int row = v >> 3, col = (v & 7) * 8;
        *(uint4*)&Opart[(((size_t)(c * 16 + pair)) * SEQ + qt * 64 + row) * 64 + col] =
            *(const uint4*)&sm[row * 72 + col];
    }
}

// ---------------- combine split-K partials -> At [B][2304][512] bf16
__global__ __launch_bounds__(256) void attn_combine(
        const u16* __restrict__ Opart, const float* __restrict__ Lpart,
        u16* __restrict__ At) {
    const int bid = blockIdx.x;
    const int pair = bid / 144, sb = bid % 144;
    const int tid = threadIdx.x;
    const int rl = tid >> 4, dg = tid & 15;
    const int s = sb * 16 + rl;
    const int b = pair >> 3, h = pair & 7;
    float wc[4], L = 0.f;
#pragma unroll
    for (int c = 0; c < 4; ++c) {
        wc[c] = Lpart[(size_t)(c * 16 + pair) * SEQ + s];
        L += wc[c];
    }
    float invL = 1.0f / L;
    float acc[4] = {0.f, 0.f, 0.f, 0.f};
#pragma unroll
    for (int c = 0; c < 4; ++c) {
        ushort4 v = *(const ushort4*)&Opart[((size_t)(c * 16 + pair) * SEQ + s) * 64 + dg * 4];
        acc[0] += wc[c] * bf2f(v.x);
        acc[1] += wc[c] * bf2f(v.y);
        acc[2] += wc[c] * bf2f(v.z);
        acc[3] += wc[c] * bf2f(v.w);
    }
    uint2 outv;
    outv.x = pkbf(acc[0] * invL, acc[1] * invL);
    outv.y = pkbf(acc[2] * invL, acc[3] * invL);
    *(uint2*)&At[((size_t)b * SEQ + s) * ND + h * 64 + dg * 4] = outv;
}

// ---------------- output projection GEMM (NT), 64x128 tiles, async staging
__global__ __launch_bounds__(256) void gemm_out_kernel(
        const u16* __restrict__ Wob, const u16* __restrict__ At,
        const float* __restrict__ bo, float* __restrict__ out) {
    __shared__ __align__(16) u16 As[64 * 64];
    __shared__ __align__(16) u16 Bs[128 * 64];
    const int n0 = blockIdx.x * 128;
    const int m0 = blockIdx.y * 64;
    const int b  = blockIdx.z;
    const int t = threadIdx.x;
    const int lane = t & 63, w = t >> 6;
    const int l16 = lane & 15, quad = lane >> 4;
    const int srow = t >> 3, scol = (t & 7) * 8;
    const u16* Ab = At + (size_t)b * SEQ * ND;

    f32x4 acc[4][2] = {};

    for (int kb = 0; kb < 512; kb += 64) {
        __syncthreads();
#pragma unroll
        for (int it = 0; it < 2; ++it) {
            int r2 = it * 32 + srow;
            cp16(&Wob[(size_t)(m0 + r2) * 512 + kb + scol], &As[r2 * 64 + scol]);
        }
#pragma unroll
        for (int it = 0; it < 4; ++it) {
            int r2 = it * 32 + srow;
            cp16(&Ab[(size_t)(n0 + r2) * 512 + kb + scol], &Bs[r2 * 64 + scol]);
        }
        __syncthreads();
#pragma unroll
        for (int kk = 0; kk < 2; ++kk) {
            short8 af[4], bfr[2];
#pragma unroll
            for (int i = 0; i < 4; ++i)
                af[i] = *(const short8*)&As[(i * 16 + l16) * 64 + kk * 32 + quad * 8];
#pragma unroll
            for (int j = 0; j < 2; ++j)
                bfr[j] = *(const short8*)&Bs[(w * 32 + j * 16 + l16) * 64 + kk * 32 + quad * 8];
#pragma unroll
            for (int i = 0; i < 4; ++i)
#pragma unroll
                for (int j = 0; j < 2; ++j)
                    acc[i][j] = mfma16(af[i], bfr[j], acc[i][j]);
        }
    }
#pragma unroll
    for (int i = 0; i < 4; ++i) {
        int cbase = m0 + i * 16 + quad * 4;
#pragma unroll
        for (int j = 0; j < 2; ++j) {
            int s = n0 + w * 32 + j * 16 + l16;
#pragma unroll
            for (int r = 0; r < 4; ++r) {
                int cc = cbase + r;
                out[((size_t)(b * 512 + cc)) * SEQ + s] = acc[i][j][r] + bo[cc];
            }
        }
    }
}

extern "C" void kernel_launch(void* const* d_in, const int* in_sizes, int n_in,
                              void* d_out, int out_size, void* d_ws, size_t ws_size,
                              hipStream_t stream) {
    const float* H  = (const float*)d_in[0];
    const float* Wq = (const float*)d_in[1];
    const float* bq = (const float*)d_in[2];
    const float* Wk = (const float*)d_in[3];
    const float* bk = (const float*)d_in[4];
    const float* Wv = (const float*)d_in[5];
    const float* bv = (const float*)d_in[6];
    const float* Wo = (const float*)d_in[7];
    const float* bo = (const float*)d_in[8];
    float* out = (float*)d_out;

    u16* ws    = (u16*)d_ws;
    u16* Wqkv  = ws;                                  // 1536*512
    u16* Wob   = Wqkv  + 1536 * 512;                  // 512*512
    u16* Xbf   = Wob   + 512 * 512;                   // 2*2304*512
    u16* Qb    = Xbf   + 2 * SEQ * CDIM;              // 16*2304*64
    u16* Kb    = Qb    + 2 * SEQ * ND;
    u16* Vb    = Kb    + 2 * SEQ * ND;
    u16* At    = Vb    + 2 * SEQ * ND;
    u16* Opart = At    + 2 * SEQ * ND;                // 64*2304*64
    float* Lpart = (float*)(Opart + 4 * 16 * SEQ * 64);

    prep_kernel<<<6400, 256, 0, stream>>>(H, Wq, Wk, Wv, Wo, Wqkv, Wob, Xbf);
    gemm_qkv_kernel<<<dim3(18, 12, 2), 256, 0, stream>>>(Wqkv, Xbf, bq, bk, bv, Qb, Kb, Vb);
    attn_partial<<<dim3(576, 4), 256, 0, stream>>>(Qb, Kb, Vb, Opart, Lpart);
    attn_combine<<<2304, 256, 0, stream>>>(Opart, Lpart, At);
    gemm_out_kernel<<<dim3(18, 8, 2), 256, 0, stream>>>(Wob, At, bo, out);
}

// Round 4
// 140.233 us; speedup vs baseline: 1.6636x; 1.1301x over previous
//
#include <hip/hip_runtime.h>
#include <hip/hip_bf16.h>

#define HEADS 8
#define DHEAD 64
#define CDIM  512
#define SEQ   2304      // 48*48
#define ND    512       // HEADS*DHEAD

typedef unsigned short u16;
typedef unsigned int   u32;
typedef __attribute__((ext_vector_type(8))) short short8;
typedef __attribute__((ext_vector_type(4))) float f32x4;

#define QSCALE 0.18033688011112043f   // 0.125 * log2(e): folded into Q so softmax is exp2

__device__ __forceinline__ u16 f2bf(float f) {
    union { float f; u32 u; } x; x.f = f;
    u32 r = x.u + 0x7FFFu + ((x.u >> 16) & 1u);   // RNE
    return (u16)(r >> 16);
}
__device__ __forceinline__ float bf2f(u16 v) {
    union { u32 u; float f; } x; x.u = ((u32)v) << 16; return x.f;
}
// pack two f32 -> two bf16 in one u32 (round-half-up via +0x8000, then v_perm byte-select)
__device__ __forceinline__ u32 pkbf(float a, float b) {
    union { float f; u32 u; } x, y; x.f = a; y.f = b;
    return __builtin_amdgcn_perm(y.u + 0x8000u, x.u + 0x8000u, 0x07060302u);
}
__device__ __forceinline__ f32x4 mfma16(short8 a, short8 b, f32x4 c) {
    return __builtin_amdgcn_mfma_f32_16x16x32_bf16(a, b, c, 0, 0, 0);
}
// async 16B global->LDS (wave-uniform base + lane*16 dest)
__device__ __forceinline__ void cp16(const void* g, void* l) {
    __builtin_amdgcn_global_load_lds(
        (const __attribute__((address_space(1))) u32*)(uintptr_t)g,
        (__attribute__((address_space(3))) u32*)(u32)(uintptr_t)l,
        16, 0, 0);
}
// LDS K-slot r holds source K row kperm_inv(r), so post-softmax P sits in PV B-frag order.
__device__ __forceinline__ int kperm_inv(int r) {
    return (r & ~0x1C) | ((r & 0x0C) << 1) | ((r & 0x10) >> 2);
}

// ---------------- fused: weight convert + x transpose
__global__ void prep_kernel(const float* __restrict__ H,
                            const float* __restrict__ Wq, const float* __restrict__ Wk,
                            const float* __restrict__ Wv, const float* __restrict__ Wo,
                            u16* __restrict__ Wqkv, u16* __restrict__ Wob,
                            u16* __restrict__ X) {
    __shared__ float tile[32][33];
    const int t = threadIdx.x;
    const int bx = blockIdx.x;
    if (bx < 4096) {
        int idx = bx * 256 + t;
        const int N1 = CDIM * ND;
        if (idx < N1)             Wqkv[idx] = f2bf(Wq[idx]);
        else if (idx < 2 * N1)    Wqkv[idx] = f2bf(Wk[idx - N1]);
        else if (idx < 3 * N1)    Wqkv[idx] = f2bf(Wv[idx - 2 * N1]);
        else                      Wob[idx - 3 * N1] = f2bf(Wo[idx - 3 * N1]);
    } else {
        int bb = bx - 4096;                       // 0..2303
        int st = bb % 72, ct = (bb / 72) % 16, b = bb / (72 * 16);
        int tx = t & 31, ty = t >> 5;
#pragma unroll
        for (int k = 0; k < 4; ++k) {
            int c = ct * 32 + ty + k * 8;
            tile[ty + k * 8][tx] = H[((size_t)b * CDIM + c) * SEQ + st * 32 + tx];
        }
        __syncthreads();
#pragma unroll
        for (int k = 0; k < 4; ++k) {
            int s = st * 32 + ty + k * 8;
            X[((size_t)b * SEQ + s) * CDIM + ct * 32 + tx] = f2bf(tile[tx][ty + k * 8]);
        }
    }
}

// ---------------- QKV projection GEMM (NT), async staging + XOR chunk swizzle
__global__ __launch_bounds__(256) void gemm_qkv_kernel(
        const u16* __restrict__ W, const u16* __restrict__ X,
        const float* __restrict__ bq, const float* __restrict__ bk, const float* __restrict__ bv,
        u16* __restrict__ Q, u16* __restrict__ K, u16* __restrict__ V) {
    __shared__ __align__(16) u16 As[128 * 64];
    __shared__ __align__(16) u16 Bs[128 * 64];
    const int n0 = blockIdx.x * 128;
    const int m0 = blockIdx.y * 128;
    const int b  = blockIdx.z;
    const int t = threadIdx.x;
    const int lane = t & 63, w = t >> 6;
    const int l16 = lane & 15, quad = lane >> 4;
    const int x7 = l16 & 7;
    const int wm = (w >> 1) * 64, wn = (w & 1) * 64;
    const int srow = t >> 3, scol = (t & 7) * 8;
    const int scol_sw = ((t & 7) ^ (srow & 7)) * 8;   // swizzled source chunk
    const u16* Xb = X + (size_t)b * SEQ * CDIM;

    f32x4 acc[4][4] = {};

    for (int kb = 0; kb < 512; kb += 64) {
        __syncthreads();
#pragma unroll
        for (int it = 0; it < 4; ++it) {
            int r2 = it * 32 + srow;
            cp16(&W [(size_t)(m0 + r2) * 512 + kb + scol_sw], &As[r2 * 64 + scol]);
            cp16(&Xb[(size_t)(n0 + r2) * 512 + kb + scol_sw], &Bs[r2 * 64 + scol]);
        }
        __syncthreads();
#pragma unroll
        for (int kk = 0; kk < 2; ++kk) {
            const int co = ((kk * 4 + quad) ^ x7) * 8;     // swizzled read chunk
            short8 af[4], bfr[4];
#pragma unroll
            for (int i = 0; i < 4; ++i)
                af[i] = *(const short8*)&As[(wm + i * 16 + l16) * 64 + co];
#pragma unroll
            for (int j = 0; j < 4; ++j)
                bfr[j] = *(const short8*)&Bs[(wn + j * 16 + l16) * 64 + co];
#pragma unroll
            for (int i = 0; i < 4; ++i)
#pragma unroll
                for (int j = 0; j < 4; ++j)
                    acc[i][j] = mfma16(af[i], bfr[j], acc[i][j]);
        }
    }

    if (m0 < 1024) {
        const bool isQ = (m0 < 512);
        const float* bias = isQ ? bq : bk;
        const float sc = isQ ? QSCALE : 1.0f;
        const int mq = isQ ? m0 : m0 - 512;
        u16* dst = isQ ? Q : K;
#pragma unroll
        for (int j = 0; j < 4; ++j) {
            int s = n0 + wn + j * 16 + l16;
#pragma unroll
            for (int i = 0; i < 4; ++i) {
                int mm = mq + wm + i * 16 + quad * 4;
                uint2 val;
                val.x = pkbf((acc[i][j][0] + bias[mm + 0]) * sc, (acc[i][j][1] + bias[mm + 1]) * sc);
                val.y = pkbf((acc[i][j][2] + bias[mm + 2]) * sc, (acc[i][j][3] + bias[mm + 3]) * sc);
                *(uint2*)&dst[(((size_t)(b * 8 + (mm >> 6))) * SEQ + s) * 64 + (mm & 63)] = val;
            }
        }
    } else {
#pragma unroll
        for (int j = 0; j < 4; ++j) {
            int s = n0 + wn + j * 16 + l16;
#pragma unroll
            for (int i = 0; i < 4; ++i) {
                int mbase = m0 - 1024 + wm + i * 16 + quad * 4;
#pragma unroll
                for (int r = 0; r < 4; ++r) {
                    int mm = mbase + r;
                    V[((size_t)(b * 512 + mm)) * SEQ + s] = f2bf(acc[i][j][r] + bv[mm]);
                }
            }
        }
    }
}

// ---------------- flash attention partial (split-K x4), 128-q blocks, swizzled LDS
__global__ __launch_bounds__(256) void attn_partial(
        const u16* __restrict__ Q,    // [16][2304][64] (pre-scaled by QSCALE)
        const u16* __restrict__ K,    // [16][2304][64]
        const u16* __restrict__ Vt,   // [B][512][2304]
        u16* __restrict__ Opart,      // [4*16][2304][64] chunk-normalized bf16
        float* __restrict__ Lpart) {  // [4*16][2304]
    __shared__ __align__(16) u16 sm[2 * 64 * 64];   // Ks | Vs
    u16* Ks = sm;
    u16* Vs = sm + 64 * 64;
    const int pair = blockIdx.x & 15, qt = blockIdx.x >> 4;   // qt 0..17 (128-q tiles)
    const int c = blockIdx.y;
    const int b = pair >> 3, h = pair & 7;
    const int t = threadIdx.x, lane = t & 63, w = t >> 6;
    const int l16 = lane & 15, quad = lane >> 4;
    const int x7 = l16 & 7;
    const int srow = t >> 3;
    const int scol = (t & 7) * 8;
    const int scol_sw = ((t & 7) ^ (srow & 7)) * 8;
    const int kinv0 = kperm_inv(srow), kinv1 = kperm_inv(32 + srow);
    const int cA = (quad ^ x7) * 8;        // swizzled chunk for logical chunk quad
    const int cB = (quad ^ x7 ^ 4) * 8;    // swizzled chunk for logical chunk quad+4

    // Q fragments for two q-groups (B-frag: n=q, k=d)
    const u16* Qg = Q + ((size_t)pair * SEQ + qt * 128) * 64;
    const int rA = w * 16 + l16, rB = 64 + rA;
    short8 qfa0 = *(const short8*)&Qg[(size_t)rA * 64 + quad * 8];
    short8 qfa1 = *(const short8*)&Qg[(size_t)rA * 64 + 32 + quad * 8];
    short8 qfb0 = *(const short8*)&Qg[(size_t)rB * 64 + quad * 8];
    short8 qfb1 = *(const short8*)&Qg[(size_t)rB * 64 + 32 + quad * 8];

    const u16* Kg = K  + ((size_t)pair * SEQ + c * 576) * 64;
    const u16* Vg = Vt + ((size_t)(b * 512 + h * 64)) * SEQ + c * 576;

    f32x4 laccA = {0.f, 0.f, 0.f, 0.f}, laccB = {0.f, 0.f, 0.f, 0.f};
    f32x4 oA[4] = {}, oB[4] = {};

    for (int kt = 0; kt < 9; ++kt) {
        __syncthreads();
        cp16(&Kg[(size_t)(kt * 64 + kinv0) * 64 + scol_sw], &Ks[srow * 64 + scol]);
        cp16(&Kg[(size_t)(kt * 64 + kinv1) * 64 + scol_sw], &Ks[(32 + srow) * 64 + scol]);
        cp16(&Vg[(size_t)srow * SEQ + kt * 64 + scol_sw],        &Vs[srow * 64 + scol]);
        cp16(&Vg[(size_t)(32 + srow) * SEQ + kt * 64 + scol_sw], &Vs[(32 + srow) * 64 + scol]);
        __syncthreads();
        // S^T = K Q^T : rows = ki (kperm'd), cols = q; each kf read feeds 2 MFMAs
        f32x4 saccA[4] = {}, saccB[4] = {};
#pragma unroll
        for (int j = 0; j < 4; ++j) {
            short8 kf0 = *(const short8*)&Ks[(j * 16 + l16) * 64 + cA];
            short8 kf1 = *(const short8*)&Ks[(j * 16 + l16) * 64 + cB];
            saccA[j] = mfma16(kf0, qfa0, saccA[j]);
            saccA[j] = mfma16(kf1, qfa1, saccA[j]);
            saccB[j] = mfma16(kf0, qfb0, saccB[j]);
            saccB[j] = mfma16(kf1, qfb1, saccB[j]);
        }
        // fixed-max softmax
        float pA[4][4], pB[4][4];
#pragma unroll
        for (int j = 0; j < 4; ++j)
#pragma unroll
            for (int r = 0; r < 4; ++r) {
                pA[j][r] = __builtin_amdgcn_exp2f(saccA[j][r]);
                laccA[j] += pA[j][r];
                pB[j][r] = __builtin_amdgcn_exp2f(saccB[j][r]);
                laccB[j] += pB[j][r];
            }
        // PV: P already in B-frag order thanks to kperm; each vf read feeds 2 MFMAs
#pragma unroll
        for (int g = 0; g < 2; ++g) {
            short8 pfA, pfB;
            u32* pwA = (u32*)&pfA;
            u32* pwB = (u32*)&pfB;
            pwA[0] = pkbf(pA[2 * g][0], pA[2 * g][1]);
            pwA[1] = pkbf(pA[2 * g][2], pA[2 * g][3]);
            pwA[2] = pkbf(pA[2 * g + 1][0], pA[2 * g + 1][1]);
            pwA[3] = pkbf(pA[2 * g + 1][2], pA[2 * g + 1][3]);
            pwB[0] = pkbf(pB[2 * g][0], pB[2 * g][1]);
            pwB[1] = pkbf(pB[2 * g][2], pB[2 * g][3]);
            pwB[2] = pkbf(pB[2 * g + 1][0], pB[2 * g + 1][1]);
            pwB[3] = pkbf(pB[2 * g + 1][2], pB[2 * g + 1][3]);
            const int cg = g ? cB : cA;
#pragma unroll
            for (int i = 0; i < 4; ++i) {
                short8 vf = *(const short8*)&Vs[(i * 16 + l16) * 64 + cg];
                oA[i] = mfma16(vf, pfA, oA[i]);
                oB[i] = mfma16(vf, pfB, oB[i]);
            }
        }
    }
    // reduce l across quads
    float lA = laccA[0] + laccA[1] + laccA[2] + laccA[3];
    lA += __shfl_xor(lA, 16); lA += __shfl_xor(lA, 32);
    float lB = laccB[0] + laccB[1] + laccB[2] + laccB[3];
    lB += __shfl_xor(lB, 16); lB += __shfl_xor(lB, 32);
    float invA = 1.0f / lA, invB = 1.0f / lB;
    const size_t orow = ((size_t)(c * 16 + pair)) * SEQ + qt * 128;

    // pass A: bounce O rows 0..63 through LDS (stride 72), coalesced store
    __syncthreads();
#pragma unroll
    for (int i = 0; i < 4; ++i) {
        uint2 pk;
        pk.x = pkbf(oA[i][0] * invA, oA[i][1] * invA);
        pk.y = pkbf(oA[i][2] * invA, oA[i][3] * invA);
        *(uint2*)&sm[(w * 16 + l16) * 72 + i * 16 + quad * 4] = pk;
    }
    if (quad == 0) Lpart[orow + w * 16 + l16] = lA;
    __syncthreads();
#pragma unroll
    for (int it = 0; it < 2; ++it) {
        int v = it * 256 + t;
        int row = v >> 3, col = (v & 7) * 8;
        *(uint4*)&Opart[(orow + row) * 64 + col] = *(const uint4*)&sm[row * 72 + col];
    }
    // pass B: rows 64..127
    __syncthreads();
#pragma unroll
    for (int i = 0; i < 4; ++i) {
        uint2 pk;
        pk.x = pkbf(oB[i][0] * invB, oB[i][1] * invB);
        pk.y = pkbf(oB[i][2] * invB, oB[i][3] * invB);
        *(uint2*)&sm[(w * 16 + l16) * 72 + i * 16 + quad * 4] = pk;
    }
    if (quad == 0) Lpart[orow + 64 + w * 16 + l16] = lB;
    __syncthreads();
#pragma unroll
    for (int it = 0; it < 2; ++it) {
        int v = it * 256 + t;
        int row = v >> 3, col = (v & 7) * 8;
        *(uint4*)&Opart[(orow + 64 + row) * 64 + col] = *(const uint4*)&sm[row * 72 + col];
    }
}

// ---------------- combine split-K partials -> At [B][2304][512] bf16
__global__ __launch_bounds__(256) void attn_combine(
        const u16* __restrict__ Opart, const float* __restrict__ Lpart,
        u16* __restrict__ At) {
    const int bid = blockIdx.x;
    const int pair = bid / 144, sb = bid % 144;
    const int tid = threadIdx.x;
    const int rl = tid >> 4, dg = tid & 15;
    const int s = sb * 16 + rl;
    const int b = pair >> 3, h = pair & 7;
    float wc[4], L = 0.f;
#pragma unroll
    for (int c = 0; c < 4; ++c) {
        wc[c] = Lpart[(size_t)(c * 16 + pair) * SEQ + s];
        L += wc[c];
    }
    float invL = 1.0f / L;
    float acc[4] = {0.f, 0.f, 0.f, 0.f};
#pragma unroll
    for (int c = 0; c < 4; ++c) {
        ushort4 v = *(const ushort4*)&Opart[((size_t)(c * 16 + pair) * SEQ + s) * 64 + dg * 4];
        acc[0] += wc[c] * bf2f(v.x);
        acc[1] += wc[c] * bf2f(v.y);
        acc[2] += wc[c] * bf2f(v.z);
        acc[3] += wc[c] * bf2f(v.w);
    }
    uint2 outv;
    outv.x = pkbf(acc[0] * invL, acc[1] * invL);
    outv.y = pkbf(acc[2] * invL, acc[3] * invL);
    *(uint2*)&At[((size_t)b * SEQ + s) * ND + h * 64 + dg * 4] = outv;
}

// ---------------- output projection GEMM (NT), 64x128 tiles, async staging + swizzle
__global__ __launch_bounds__(256) void gemm_out_kernel(
        const u16* __restrict__ Wob, const u16* __restrict__ At,
        const float* __restrict__ bo, float* __restrict__ out) {
    __shared__ __align__(16) u16 As[64 * 64];
    __shared__ __align__(16) u16 Bs[128 * 64];
    const int n0 = blockIdx.x * 128;
    const int m0 = blockIdx.y * 64;
    const int b  = blockIdx.z;
    const int t = threadIdx.x;
    const int lane = t & 63, w = t >> 6;
    const int l16 = lane & 15, quad = lane >> 4;
    const int x7 = l16 & 7;
    const int srow = t >> 3, scol = (t & 7) * 8;
    const int scol_sw = ((t & 7) ^ (srow & 7)) * 8;
    const u16* Ab = At + (size_t)b * SEQ * ND;

    f32x4 acc[4][2] = {};

    for (int kb = 0; kb < 512; kb += 64) {
        __syncthreads();
#pragma unroll
        for (int it = 0; it < 2; ++it) {
            int r2 = it * 32 + srow;
            cp16(&Wob[(size_t)(m0 + r2) * 512 + kb + scol_sw], &As[r2 * 64 + scol]);
        }
#pragma unroll
        for (int it = 0; it < 4; ++it) {
            int r2 = it * 32 + srow;
            cp16(&Ab[(size_t)(n0 + r2) * 512 + kb + scol_sw], &Bs[r2 * 64 + scol]);
        }
        __syncthreads();
#pragma unroll
        for (int kk = 0; kk < 2; ++kk) {
            const int co = ((kk * 4 + quad) ^ x7) * 8;
            short8 af[4], bfr[2];
#pragma unroll
            for (int i = 0; i < 4; ++i)
                af[i] = *(const short8*)&As[(i * 16 + l16) * 64 + co];
#pragma unroll
            for (int j = 0; j < 2; ++j)
                bfr[j] = *(const short8*)&Bs[(w * 32 + j * 16 + l16) * 64 + co];
#pragma unroll
            for (int i = 0; i < 4; ++i)
#pragma unroll
                for (int j = 0; j < 2; ++j)
                    acc[i][j] = mfma16(af[i], bfr[j], acc[i][j]);
        }
    }
#pragma unroll
    for (int i = 0; i < 4; ++i) {
        int cbase = m0 + i * 16 + quad * 4;
#pragma unroll
        for (int j = 0; j < 2; ++j) {
            int s = n0 + w * 32 + j * 16 + l16;
#pragma unroll
            for (int r = 0; r < 4; ++r) {
                int cc = cbase + r;
                out[((size_t)(b * 512 + cc)) * SEQ + s] = acc[i][j][r] + bo[cc];
            }
        }
    }
}

extern "C" void kernel_launch(void* const* d_in, const int* in_sizes, int n_in,
                              void* d_out, int out_size, void* d_ws, size_t ws_size,
                              hipStream_t stream) {
    const float* H  = (const float*)d_in[0];
    const float* Wq = (const float*)d_in[1];
    const float* bq = (const float*)d_in[2];
    const float* Wk = (const float*)d_in[3];
    const float* bk = (const float*)d_in[4];
    const float* Wv = (const float*)d_in[5];
    const float* bv = (const float*)d_in[6];
    const float* Wo = (const float*)d_in[7];
    const float* bo = (const float*)d_in[8];
    float* out = (float*)d_out;

    u16* ws    = (u16*)d_ws;
    u16* Wqkv  = ws;                                  // 1536*512
    u16* Wob   = Wqkv  + 1536 * 512;                  // 512*512
    u16* Xbf   = Wob   + 512 * 512;                   // 2*2304*512
    u16* Qb    = Xbf   + 2 * SEQ * CDIM;              // 16*2304*64
    u16* Kb    = Qb    + 2 * SEQ * ND;
    u16* Vb    = Kb    + 2 * SEQ * ND;
    u16* At    = Vb    + 2 * SEQ * ND;
    u16* Opart = At    + 2 * SEQ * ND;                // 64*2304*64
    float* Lpart = (float*)(Opart + 4 * 16 * SEQ * 64);

    prep_kernel<<<6400, 256, 0, stream>>>(H, Wq, Wk, Wv, Wo, Wqkv, Wob, Xbf);
    gemm_qkv_kernel<<<dim3(18, 12, 2), 256, 0, stream>>>(Wqkv, Xbf, bq, bk, bv, Qb, Kb, Vb);
    attn_partial<<<dim3(288, 4), 256, 0, stream>>>(Qb, Kb, Vb, Opart, Lpart);
    attn_combine<<<2304, 256, 0, stream>>>(Opart, Lpart, At);
    gemm_out_kernel<<<dim3(18, 8, 2), 256, 0, stream>>>(Wob, At, bo, out);
}

// Round 5
// 135.826 us; speedup vs baseline: 1.7175x; 1.0324x over previous
//
#include <hip/hip_runtime.h>
#include <hip/hip_bf16.h>

#define HEADS 8
#define DHEAD 64
#define CDIM  512
#define SEQ   2304      // 48*48
#define ND    512       // HEADS*DHEAD

typedef unsigned short u16;
typedef unsigned int   u32;
typedef __attribute__((ext_vector_type(8))) short short8;
typedef __attribute__((ext_vector_type(4))) float f32x4;

#define QSCALE 0.18033688011112043f   // 0.125 * log2(e): folded into Q so softmax is exp2

__device__ __forceinline__ u16 f2bf(float f) {
    union { float f; u32 u; } x; x.f = f;
    u32 r = x.u + 0x7FFFu + ((x.u >> 16) & 1u);   // RNE
    return (u16)(r >> 16);
}
__device__ __forceinline__ float bf2f(u16 v) {
    union { u32 u; float f; } x; x.u = ((u32)v) << 16; return x.f;
}
// pack two f32 -> two bf16 in one u32 (round-half-up via +0x8000, then v_perm byte-select)
__device__ __forceinline__ u32 pkbf(float a, float b) {
    union { float f; u32 u; } x, y; x.f = a; y.f = b;
    return __builtin_amdgcn_perm(y.u + 0x8000u, x.u + 0x8000u, 0x07060302u);
}
__device__ __forceinline__ f32x4 mfma16(short8 a, short8 b, f32x4 c) {
    return __builtin_amdgcn_mfma_f32_16x16x32_bf16(a, b, c, 0, 0, 0);
}
// async 16B global->LDS (wave-uniform base + lane*16 dest)
__device__ __forceinline__ void cp16(const void* g, void* l) {
    __builtin_amdgcn_global_load_lds(
        (const __attribute__((address_space(1))) u32*)(uintptr_t)g,
        (__attribute__((address_space(3))) u32*)(u32)(uintptr_t)l,
        16, 0, 0);
}
// LDS K-slot r holds source K row kperm_inv(r), so post-softmax P sits in PV B-frag order.
__device__ __forceinline__ int kperm_inv(int r) {
    return (r & ~0x1C) | ((r & 0x0C) << 1) | ((r & 0x10) >> 2);
}

// ---------------- fused: weight convert + x transpose
__global__ void prep_kernel(const float* __restrict__ H,
                            const float* __restrict__ Wq, const float* __restrict__ Wk,
                            const float* __restrict__ Wv, const float* __restrict__ Wo,
                            u16* __restrict__ Wqkv, u16* __restrict__ Wob,
                            u16* __restrict__ X) {
    __shared__ float tile[32][33];
    const int t = threadIdx.x;
    const int bx = blockIdx.x;
    if (bx < 4096) {
        int idx = bx * 256 + t;
        const int N1 = CDIM * ND;
        if (idx < N1)             Wqkv[idx] = f2bf(Wq[idx]);
        else if (idx < 2 * N1)    Wqkv[idx] = f2bf(Wk[idx - N1]);
        else if (idx < 3 * N1)    Wqkv[idx] = f2bf(Wv[idx - 2 * N1]);
        else                      Wob[idx - 3 * N1] = f2bf(Wo[idx - 3 * N1]);
    } else {
        int bb = bx - 4096;                       // 0..2303
        int st = bb % 72, ct = (bb / 72) % 16, b = bb / (72 * 16);
        int tx = t & 31, ty = t >> 5;
#pragma unroll
        for (int k = 0; k < 4; ++k) {
            int c = ct * 32 + ty + k * 8;
            tile[ty + k * 8][tx] = H[((size_t)b * CDIM + c) * SEQ + st * 32 + tx];
        }
        __syncthreads();
#pragma unroll
        for (int k = 0; k < 4; ++k) {
            int s = st * 32 + ty + k * 8;
            X[((size_t)b * SEQ + s) * CDIM + ct * 32 + tx] = f2bf(tile[tx][ty + k * 8]);
        }
    }
}

// ---------------- QKV projection GEMM (NT), 64x128 tiles, double-buffered async staging
__global__ __launch_bounds__(256) void gemm_qkv_kernel(
        const u16* __restrict__ W, const u16* __restrict__ X,
        const float* __restrict__ bq, const float* __restrict__ bk, const float* __restrict__ bv,
        u16* __restrict__ Q, u16* __restrict__ K, u16* __restrict__ V) {
    __shared__ __align__(16) u16 sm[2 * (64 * 64 + 128 * 64)];   // 48 KB: [buf][As|Bs]
    const int n0 = blockIdx.x * 128;
    const int m0 = blockIdx.y * 64;
    const int b  = blockIdx.z;
    const int t = threadIdx.x;
    const int lane = t & 63, w = t >> 6;
    const int l16 = lane & 15, quad = lane >> 4;
    const int x7 = l16 & 7;
    const int srow = t >> 3, scol = (t & 7) * 8;
    const int scol_sw = ((t & 7) ^ (srow & 7)) * 8;   // swizzled source chunk
    const u16* Xb = X + (size_t)b * SEQ * CDIM;

    f32x4 acc[4][2] = {};

    // preload kb=0 into buf 0
    {
        u16* As = sm; u16* Bs = sm + 64 * 64;
#pragma unroll
        for (int it = 0; it < 2; ++it) {
            int r2 = it * 32 + srow;
            cp16(&W[(size_t)(m0 + r2) * 512 + scol_sw], &As[r2 * 64 + scol]);
        }
#pragma unroll
        for (int it = 0; it < 4; ++it) {
            int r2 = it * 32 + srow;
            cp16(&Xb[(size_t)(n0 + r2) * 512 + scol_sw], &Bs[r2 * 64 + scol]);
        }
    }
    for (int kb = 0; kb < 512; kb += 64) {
        const int pb = (kb >> 6) & 1;
        u16* As = sm + pb * 12288;
        u16* Bs = As + 64 * 64;
        __syncthreads();                               // buf pb ready (vmcnt drain)
        if (kb + 64 < 512) {                           // prefetch next into buf pb^1
            u16* An = sm + (pb ^ 1) * 12288;
            u16* Bn = An + 64 * 64;
#pragma unroll
            for (int it = 0; it < 2; ++it) {
                int r2 = it * 32 + srow;
                cp16(&W[(size_t)(m0 + r2) * 512 + kb + 64 + scol_sw], &An[r2 * 64 + scol]);
            }
#pragma unroll
            for (int it = 0; it < 4; ++it) {
                int r2 = it * 32 + srow;
                cp16(&Xb[(size_t)(n0 + r2) * 512 + kb + 64 + scol_sw], &Bn[r2 * 64 + scol]);
            }
        }
#pragma unroll
        for (int kk = 0; kk < 2; ++kk) {
            const int co = ((kk * 4 + quad) ^ x7) * 8;
            short8 af[4], bfr[2];
#pragma unroll
            for (int i = 0; i < 4; ++i)
                af[i] = *(const short8*)&As[(i * 16 + l16) * 64 + co];
#pragma unroll
            for (int j = 0; j < 2; ++j)
                bfr[j] = *(const short8*)&Bs[(w * 32 + j * 16 + l16) * 64 + co];
#pragma unroll
            for (int i = 0; i < 4; ++i)
#pragma unroll
                for (int j = 0; j < 2; ++j)
                    acc[i][j] = mfma16(af[i], bfr[j], acc[i][j]);
        }
    }

    if (m0 < 1024) {
        const bool isQ = (m0 < 512);
        const float* bias = isQ ? bq : bk;
        const float sc = isQ ? QSCALE : 1.0f;
        const int mq = isQ ? m0 : m0 - 512;
        u16* dst = isQ ? Q : K;
#pragma unroll
        for (int j = 0; j < 2; ++j) {
            int s = n0 + w * 32 + j * 16 + l16;
#pragma unroll
            for (int i = 0; i < 4; ++i) {
                int mm = mq + i * 16 + quad * 4;
                uint2 val;
                val.x = pkbf((acc[i][j][0] + bias[mm + 0]) * sc, (acc[i][j][1] + bias[mm + 1]) * sc);
                val.y = pkbf((acc[i][j][2] + bias[mm + 2]) * sc, (acc[i][j][3] + bias[mm + 3]) * sc);
                *(uint2*)&dst[(((size_t)(b * 8 + (mm >> 6))) * SEQ + s) * 64 + (mm & 63)] = val;
            }
        }
    } else {
#pragma unroll
        for (int j = 0; j < 2; ++j) {
            int s = n0 + w * 32 + j * 16 + l16;
#pragma unroll
            for (int i = 0; i < 4; ++i) {
                int mbase = m0 - 1024 + i * 16 + quad * 4;
#pragma unroll
                for (int r = 0; r < 4; ++r) {
                    int mm = mbase + r;
                    V[((size_t)(b * 512 + mm)) * SEQ + s] = f2bf(acc[i][j][r] + bv[mm]);
                }
            }
        }
    }
}

// ---------------- flash attention partial (split-K x4), 128-q blocks, dbuf K/V
__global__ __launch_bounds__(256) void attn_partial(
        const u16* __restrict__ Q,    // [16][2304][64] (pre-scaled by QSCALE)
        const u16* __restrict__ K,    // [16][2304][64]
        const u16* __restrict__ Vt,   // [B][512][2304]
        u16* __restrict__ Opart,      // [4*16][2304][64] chunk-normalized bf16
        float* __restrict__ Lpart) {  // [4*16][2304]
    __shared__ __align__(16) u16 sm[2 * 8192];      // 32 KB: [buf][Ks|Vs], each 64x64
    const int pair = blockIdx.x & 15, qt = blockIdx.x >> 4;   // qt 0..17 (128-q tiles)
    const int c = blockIdx.y;
    const int b = pair >> 3, h = pair & 7;
    const int t = threadIdx.x, lane = t & 63, w = t >> 6;
    const int l16 = lane & 15, quad = lane >> 4;
    const int x7 = l16 & 7;
    const int srow = t >> 3;
    const int scol = (t & 7) * 8;
    const int scol_sw = ((t & 7) ^ (srow & 7)) * 8;
    const int kinv0 = kperm_inv(srow), kinv1 = kperm_inv(32 + srow);
    const int cA = (quad ^ x7) * 8;        // swizzled chunk for logical chunk quad
    const int cB = (quad ^ x7 ^ 4) * 8;    // swizzled chunk for logical chunk quad+4

    // Q fragments for two q-groups (B-frag: n=q, k=d)
    const u16* Qg = Q + ((size_t)pair * SEQ + qt * 128) * 64;
    const int rA = w * 16 + l16, rB = 64 + rA;
    short8 qfa0 = *(const short8*)&Qg[(size_t)rA * 64 + quad * 8];
    short8 qfa1 = *(const short8*)&Qg[(size_t)rA * 64 + 32 + quad * 8];
    short8 qfb0 = *(const short8*)&Qg[(size_t)rB * 64 + quad * 8];
    short8 qfb1 = *(const short8*)&Qg[(size_t)rB * 64 + 32 + quad * 8];

    const u16* Kg = K  + ((size_t)pair * SEQ + c * 576) * 64;
    const u16* Vg = Vt + ((size_t)(b * 512 + h * 64)) * SEQ + c * 576;

    f32x4 laccA = {0.f, 0.f, 0.f, 0.f}, laccB = {0.f, 0.f, 0.f, 0.f};
    f32x4 oA[4] = {}, oB[4] = {};

    // preload kt=0 into buf 0
    {
        u16* Ks = sm; u16* Vs = sm + 4096;
        cp16(&Kg[(size_t)kinv0 * 64 + scol_sw], &Ks[srow * 64 + scol]);
        cp16(&Kg[(size_t)kinv1 * 64 + scol_sw], &Ks[(32 + srow) * 64 + scol]);
        cp16(&Vg[(size_t)srow * SEQ + scol_sw],        &Vs[srow * 64 + scol]);
        cp16(&Vg[(size_t)(32 + srow) * SEQ + scol_sw], &Vs[(32 + srow) * 64 + scol]);
    }
    for (int kt = 0; kt < 9; ++kt) {
        const int pb = kt & 1;
        const u16* Ks = sm + pb * 8192;
        const u16* Vs = Ks + 4096;
        __syncthreads();                              // buf pb ready
        if (kt < 8) {                                 // prefetch kt+1 into buf pb^1
            u16* Kn = sm + (pb ^ 1) * 8192;
            u16* Vn = Kn + 4096;
            cp16(&Kg[(size_t)((kt + 1) * 64 + kinv0) * 64 + scol_sw], &Kn[srow * 64 + scol]);
            cp16(&Kg[(size_t)((kt + 1) * 64 + kinv1) * 64 + scol_sw], &Kn[(32 + srow) * 64 + scol]);
            cp16(&Vg[(size_t)srow * SEQ + (kt + 1) * 64 + scol_sw],        &Vn[srow * 64 + scol]);
            cp16(&Vg[(size_t)(32 + srow) * SEQ + (kt + 1) * 64 + scol_sw], &Vn[(32 + srow) * 64 + scol]);
        }
        // S^T = K Q^T : rows = ki (kperm'd), cols = q; each kf read feeds 2 MFMAs
        f32x4 saccA[4] = {}, saccB[4] = {};
#pragma unroll
        for (int j = 0; j < 4; ++j) {
            short8 kf0 = *(const short8*)&Ks[(j * 16 + l16) * 64 + cA];
            short8 kf1 = *(const short8*)&Ks[(j * 16 + l16) * 64 + cB];
            saccA[j] = mfma16(kf0, qfa0, saccA[j]);
            saccA[j] = mfma16(kf1, qfa1, saccA[j]);
            saccB[j] = mfma16(kf0, qfb0, saccB[j]);
            saccB[j] = mfma16(kf1, qfb1, saccB[j]);
        }
        // fixed-max softmax
        float pA[4][4], pB[4][4];
#pragma unroll
        for (int j = 0; j < 4; ++j)
#pragma unroll
            for (int r = 0; r < 4; ++r) {
                pA[j][r] = __builtin_amdgcn_exp2f(saccA[j][r]);
                laccA[j] += pA[j][r];
                pB[j][r] = __builtin_amdgcn_exp2f(saccB[j][r]);
                laccB[j] += pB[j][r];
            }
        // PV: P already in B-frag order thanks to kperm; each vf read feeds 2 MFMAs
#pragma unroll
        for (int g = 0; g < 2; ++g) {
            short8 pfA, pfB;
            u32* pwA = (u32*)&pfA;
            u32* pwB = (u32*)&pfB;
            pwA[0] = pkbf(pA[2 * g][0], pA[2 * g][1]);
            pwA[1] = pkbf(pA[2 * g][2], pA[2 * g][3]);
            pwA[2] = pkbf(pA[2 * g + 1][0], pA[2 * g + 1][1]);
            pwA[3] = pkbf(pA[2 * g + 1][2], pA[2 * g + 1][3]);
            pwB[0] = pkbf(pB[2 * g][0], pB[2 * g][1]);
            pwB[1] = pkbf(pB[2 * g][2], pB[2 * g][3]);
            pwB[2] = pkbf(pB[2 * g + 1][0], pB[2 * g + 1][1]);
            pwB[3] = pkbf(pB[2 * g + 1][2], pB[2 * g + 1][3]);
            const int cg = g ? cB : cA;
#pragma unroll
            for (int i = 0; i < 4; ++i) {
                short8 vf = *(const short8*)&Vs[(i * 16 + l16) * 64 + cg];
                oA[i] = mfma16(vf, pfA, oA[i]);
                oB[i] = mfma16(vf, pfB, oB[i]);
            }
        }
    }
    // reduce l across quads
    float lA = laccA[0] + laccA[1] + laccA[2] + laccA[3];
    lA += __shfl_xor(lA, 16); lA += __shfl_xor(lA, 32);
    float lB = laccB[0] + laccB[1] + laccB[2] + laccB[3];
    lB += __shfl_xor(lB, 16); lB += __shfl_xor(lB, 32);
    float invA = 1.0f / lA, invB = 1.0f / lB;
    const size_t orow = ((size_t)(c * 16 + pair)) * SEQ + qt * 128;

    // single merged bounce: 128 rows x 72 stride in the (now free) dbuf LDS
    __syncthreads();
#pragma unroll
    for (int i = 0; i < 4; ++i) {
        uint2 pka, pkb;
        pka.x = pkbf(oA[i][0] * invA, oA[i][1] * invA);
        pka.y = pkbf(oA[i][2] * invA, oA[i][3] * invA);
        pkb.x = pkbf(oB[i][0] * invB, oB[i][1] * invB);
        pkb.y = pkbf(oB[i][2] * invB, oB[i][3] * invB);
        *(uint2*)&sm[(w * 16 + l16) * 72 + i * 16 + quad * 4] = pka;
        *(uint2*)&sm[(64 + w * 16 + l16) * 72 + i * 16 + quad * 4] = pkb;
    }
    if (quad == 0) {
        Lpart[orow + w * 16 + l16] = lA;
        Lpart[orow + 64 + w * 16 + l16] = lB;
    }
    __syncthreads();
#pragma unroll
    for (int it = 0; it < 4; ++it) {
        int v = it * 256 + t;
        int row = v >> 3, col = (v & 7) * 8;
        *(uint4*)&Opart[(orow + row) * 64 + col] = *(const uint4*)&sm[row * 72 + col];
    }
}

// ---------------- combine split-K partials -> At [B][2304][512] bf16
__global__ __launch_bounds__(256) void attn_combine(
        const u16* __restrict__ Opart, const float* __restrict__ Lpart,
        u16* __restrict__ At) {
    const int bid = blockIdx.x;
    const int pair = bid / 144, sb = bid % 144;
    const int tid = threadIdx.x;
    const int rl = tid >> 4, dg = tid & 15;
    const int s = sb * 16 + rl;
    const int b = pair >> 3, h = pair & 7;
    float wc[4], L = 0.f;
#pragma unroll
    for (int c = 0; c < 4; ++c) {
        wc[c] = Lpart[(size_t)(c * 16 + pair) * SEQ + s];
        L += wc[c];
    }
    float invL = 1.0f / L;
    float acc[4] = {0.f, 0.f, 0.f, 0.f};
#pragma unroll
    for (int c = 0; c < 4; ++c) {
        ushort4 v = *(const ushort4*)&Opart[((size_t)(c * 16 + pair) * SEQ + s) * 64 + dg * 4];
        acc[0] += wc[c] * bf2f(v.x);
        acc[1] += wc[c] * bf2f(v.y);
        acc[2] += wc[c] * bf2f(v.z);
        acc[3] += wc[c] * bf2f(v.w);
    }
    uint2 outv;
    outv.x = pkbf(acc[0] * invL, acc[1] * invL);
    outv.y = pkbf(acc[2] * invL, acc[3] * invL);
    *(uint2*)&At[((size_t)b * SEQ + s) * ND + h * 64 + dg * 4] = outv;
}

// ---------------- output projection GEMM (NT), 64x64 tiles, dbuf async staging
__global__ __launch_bounds__(256) void gemm_out_kernel(
        const u16* __restrict__ Wob, const u16* __restrict__ At,
        const float* __restrict__ bo, float* __restrict__ out) {
    __shared__ __align__(16) u16 sm[2 * 8192];       // 32 KB: [buf][As|Bs], each 64x64
    const int n0 = blockIdx.x * 64;
    const int m0 = blockIdx.y * 64;
    const int b  = blockIdx.z;
    const int t = threadIdx.x;
    const int lane = t & 63, w = t >> 6;
    const int l16 = lane & 15, quad = lane >> 4;
    const int x7 = l16 & 7;
    const int srow = t >> 3, scol = (t & 7) * 8;
    const int scol_sw = ((t & 7) ^ (srow & 7)) * 8;
    const u16* Ab = At + (size_t)b * SEQ * ND;

    f32x4 acc[4] = {};

    {
        u16* As = sm; u16* Bs = sm + 4096;
#pragma unroll
        for (int it = 0; it < 2; ++it) {
            int r2 = it * 32 + srow;
            cp16(&Wob[(size_t)(m0 + r2) * 512 + scol_sw], &As[r2 * 64 + scol]);
            cp16(&Ab [(size_t)(n0 + r2) * 512 + scol_sw], &Bs[r2 * 64 + scol]);
        }
    }
    for (int kb = 0; kb < 512; kb += 64) {
        const int pb = (kb >> 6) & 1;
        const u16* As = sm + pb * 8192;
        const u16* Bs = As + 4096;
        __syncthreads();
        if (kb + 64 < 512) {
            u16* An = sm + (pb ^ 1) * 8192;
            u16* Bn = An + 4096;
#pragma unroll
            for (int it = 0; it < 2; ++it) {
                int r2 = it * 32 + srow;
                cp16(&Wob[(size_t)(m0 + r2) * 512 + kb + 64 + scol_sw], &An[r2 * 64 + scol]);
                cp16(&Ab [(size_t)(n0 + r2) * 512 + kb + 64 + scol_sw], &Bn[r2 * 64 + scol]);
            }
        }
#pragma unroll
        for (int kk = 0; kk < 2; ++kk) {
            const int co = ((kk * 4 + quad) ^ x7) * 8;
            short8 af[4];
#pragma unroll
            for (int i = 0; i < 4; ++i)
                af[i] = *(const short8*)&As[(i * 16 + l16) * 64 + co];
            short8 bfr = *(const short8*)&Bs[(w * 16 + l16) * 64 + co];
#pragma unroll
            for (int i = 0; i < 4; ++i)
                acc[i] = mfma16(af[i], bfr, acc[i]);
        }
    }
#pragma unroll
    for (int i = 0; i < 4; ++i) {
        int cbase = m0 + i * 16 + quad * 4;
        int s = n0 + w * 16 + l16;
#pragma unroll
        for (int r = 0; r < 4; ++r) {
            int cc = cbase + r;
            out[((size_t)(b * 512 + cc)) * SEQ + s] = acc[i][r] + bo[cc];
        }
    }
}

extern "C" void kernel_launch(void* const* d_in, const int* in_sizes, int n_in,
                              void* d_out, int out_size, void* d_ws, size_t ws_size,
                              hipStream_t stream) {
    const float* H  = (const float*)d_in[0];
    const float* Wq = (const float*)d_in[1];
    const float* bq = (const float*)d_in[2];
    const float* Wk = (const float*)d_in[3];
    const float* bk = (const float*)d_in[4];
    const float* Wv = (const float*)d_in[5];
    const float* bv = (const float*)d_in[6];
    const float* Wo = (const float*)d_in[7];
    const float* bo = (const float*)d_in[8];
    float* out = (float*)d_out;

    u16* ws    = (u16*)d_ws;
    u16* Wqkv  = ws;                                  // 1536*512
    u16* Wob   = Wqkv  + 1536 * 512;                  // 512*512
    u16* Xbf   = Wob   + 512 * 512;                   // 2*2304*512
    u16* Qb    = Xbf   + 2 * SEQ * CDIM;              // 16*2304*64
    u16* Kb    = Qb    + 2 * SEQ * ND;
    u16* Vb    = Kb    + 2 * SEQ * ND;
    u16* At    = Vb    + 2 * SEQ * ND;
    u16* Opart = At    + 2 * SEQ * ND;                // 64*2304*64
    float* Lpart = (float*)(Opart + 4 * 16 * SEQ * 64);

    prep_kernel<<<6400, 256, 0, stream>>>(H, Wq, Wk, Wv, Wo, Wqkv, Wob, Xbf);
    gemm_qkv_kernel<<<dim3(18, 24, 2), 256, 0, stream>>>(Wqkv, Xbf, bq, bk, bv, Qb, Kb, Vb);
    attn_partial<<<dim3(288, 4), 256, 0, stream>>>(Qb, Kb, Vb, Opart, Lpart);
    attn_combine<<<2304, 256, 0, stream>>>(Opart, Lpart, At);
    gemm_out_kernel<<<dim3(36, 8, 2), 256, 0, stream>>>(Wob, At, bo, out);
}

// Round 6
// 135.008 us; speedup vs baseline: 1.7279x; 1.0061x over previous
//
#include <hip/hip_runtime.h>
#include <hip/hip_bf16.h>

#define HEADS 8
#define DHEAD 64
#define CDIM  512
#define SEQ   2304      // 48*48
#define ND    512       // HEADS*DHEAD

typedef unsigned short u16;
typedef unsigned int   u32;
typedef __attribute__((ext_vector_type(8))) short short8;
typedef __attribute__((ext_vector_type(4))) float f32x4;

#define QSCALE 0.18033688011112043f   // 0.125 * log2(e): folded into Q so softmax is exp2

__device__ __forceinline__ u16 f2bf(float f) {
    union { float f; u32 u; } x; x.f = f;
    u32 r = x.u + 0x7FFFu + ((x.u >> 16) & 1u);   // RNE
    return (u16)(r >> 16);
}
__device__ __forceinline__ float bf2f(u16 v) {
    union { u32 u; float f; } x; x.u = ((u32)v) << 16; return x.f;
}
// pack two f32 -> two bf16 in one u32 (round-half-up via +0x8000, then v_perm byte-select)
__device__ __forceinline__ u32 pkbf(float a, float b) {
    union { float f; u32 u; } x, y; x.f = a; y.f = b;
    return __builtin_amdgcn_perm(y.u + 0x8000u, x.u + 0x8000u, 0x07060302u);
}
__device__ __forceinline__ f32x4 mfma16(short8 a, short8 b, f32x4 c) {
    return __builtin_amdgcn_mfma_f32_16x16x32_bf16(a, b, c, 0, 0, 0);
}
// async 16B global->LDS (wave-uniform base + lane*16 dest)
__device__ __forceinline__ void cp16(const void* g, void* l) {
    __builtin_amdgcn_global_load_lds(
        (const __attribute__((address_space(1))) u32*)(uintptr_t)g,
        (__attribute__((address_space(3))) u32*)(u32)(uintptr_t)l,
        16, 0, 0);
}
// LDS K-slot r holds source K row kperm_inv(r), so post-softmax P sits in PV B-frag order.
__device__ __forceinline__ int kperm_inv(int r) {
    return (r & ~0x1C) | ((r & 0x0C) << 1) | ((r & 0x10) >> 2);
}

// ---------------- fused: weight convert + x transpose
__global__ void prep_kernel(const float* __restrict__ H,
                            const float* __restrict__ Wq, const float* __restrict__ Wk,
                            const float* __restrict__ Wv, const float* __restrict__ Wo,
                            u16* __restrict__ Wqkv, u16* __restrict__ Wob,
                            u16* __restrict__ X) {
    __shared__ float tile[32][33];
    const int t = threadIdx.x;
    const int bx = blockIdx.x;
    if (bx < 4096) {
        int idx = bx * 256 + t;
        const int N1 = CDIM * ND;
        if (idx < N1)             Wqkv[idx] = f2bf(Wq[idx]);
        else if (idx < 2 * N1)    Wqkv[idx] = f2bf(Wk[idx - N1]);
        else if (idx < 3 * N1)    Wqkv[idx] = f2bf(Wv[idx - 2 * N1]);
        else                      Wob[idx - 3 * N1] = f2bf(Wo[idx - 3 * N1]);
    } else {
        int bb = bx - 4096;                       // 0..2303
        int st = bb % 72, ct = (bb / 72) % 16, b = bb / (72 * 16);
        int tx = t & 31, ty = t >> 5;
#pragma unroll
        for (int k = 0; k < 4; ++k) {
            int c = ct * 32 + ty + k * 8;
            tile[ty + k * 8][tx] = H[((size_t)b * CDIM + c) * SEQ + st * 32 + tx];
        }
        __syncthreads();
#pragma unroll
        for (int k = 0; k < 4; ++k) {
            int s = st * 32 + ty + k * 8;
            X[((size_t)b * SEQ + s) * CDIM + ct * 32 + tx] = f2bf(tile[tx][ty + k * 8]);
        }
    }
}

// ---------------- QKV projection GEMM (NT), 64x128 tiles, double-buffered async staging
__global__ __launch_bounds__(256) void gemm_qkv_kernel(
        const u16* __restrict__ W, const u16* __restrict__ X,
        const float* __restrict__ bq, const float* __restrict__ bk, const float* __restrict__ bv,
        u16* __restrict__ Q, u16* __restrict__ K, u16* __restrict__ V) {
    __shared__ __align__(16) u16 sm[2 * (64 * 64 + 128 * 64)];   // 48 KB: [buf][As|Bs]
    const int n0 = blockIdx.x * 128;
    const int m0 = blockIdx.y * 64;
    const int b  = blockIdx.z;
    const int t = threadIdx.x;
    const int lane = t & 63, w = t >> 6;
    const int l16 = lane & 15, quad = lane >> 4;
    const int x7 = l16 & 7;
    const int srow = t >> 3, scol = (t & 7) * 8;
    const int scol_sw = ((t & 7) ^ (srow & 7)) * 8;   // swizzled source chunk
    const u16* Xb = X + (size_t)b * SEQ * CDIM;

    f32x4 acc[4][2] = {};

    // preload kb=0 into buf 0
    {
        u16* As = sm; u16* Bs = sm + 64 * 64;
#pragma unroll
        for (int it = 0; it < 2; ++it) {
            int r2 = it * 32 + srow;
            cp16(&W[(size_t)(m0 + r2) * 512 + scol_sw], &As[r2 * 64 + scol]);
        }
#pragma unroll
        for (int it = 0; it < 4; ++it) {
            int r2 = it * 32 + srow;
            cp16(&Xb[(size_t)(n0 + r2) * 512 + scol_sw], &Bs[r2 * 64 + scol]);
        }
    }
    for (int kb = 0; kb < 512; kb += 64) {
        const int pb = (kb >> 6) & 1;
        u16* As = sm + pb * 12288;
        u16* Bs = As + 64 * 64;
        __syncthreads();                               // buf pb ready (vmcnt drain)
        if (kb + 64 < 512) {                           // prefetch next into buf pb^1
            u16* An = sm + (pb ^ 1) * 12288;
            u16* Bn = An + 64 * 64;
#pragma unroll
            for (int it = 0; it < 2; ++it) {
                int r2 = it * 32 + srow;
                cp16(&W[(size_t)(m0 + r2) * 512 + kb + 64 + scol_sw], &An[r2 * 64 + scol]);
            }
#pragma unroll
            for (int it = 0; it < 4; ++it) {
                int r2 = it * 32 + srow;
                cp16(&Xb[(size_t)(n0 + r2) * 512 + kb + 64 + scol_sw], &Bn[r2 * 64 + scol]);
            }
        }
#pragma unroll
        for (int kk = 0; kk < 2; ++kk) {
            const int co = ((kk * 4 + quad) ^ x7) * 8;
            short8 af[4], bfr[2];
#pragma unroll
            for (int i = 0; i < 4; ++i)
                af[i] = *(const short8*)&As[(i * 16 + l16) * 64 + co];
#pragma unroll
            for (int j = 0; j < 2; ++j)
                bfr[j] = *(const short8*)&Bs[(w * 32 + j * 16 + l16) * 64 + co];
#pragma unroll
            for (int i = 0; i < 4; ++i)
#pragma unroll
                for (int j = 0; j < 2; ++j)
                    acc[i][j] = mfma16(af[i], bfr[j], acc[i][j]);
        }
    }

    if (m0 < 1024) {
        const bool isQ = (m0 < 512);
        const float* bias = isQ ? bq : bk;
        const float sc = isQ ? QSCALE : 1.0f;
        const int mq = isQ ? m0 : m0 - 512;
        u16* dst = isQ ? Q : K;
#pragma unroll
        for (int j = 0; j < 2; ++j) {
            int s = n0 + w * 32 + j * 16 + l16;
#pragma unroll
            for (int i = 0; i < 4; ++i) {
                int mm = mq + i * 16 + quad * 4;
                uint2 val;
                val.x = pkbf((acc[i][j][0] + bias[mm + 0]) * sc, (acc[i][j][1] + bias[mm + 1]) * sc);
                val.y = pkbf((acc[i][j][2] + bias[mm + 2]) * sc, (acc[i][j][3] + bias[mm + 3]) * sc);
                *(uint2*)&dst[(((size_t)(b * 8 + (mm >> 6))) * SEQ + s) * 64 + (mm & 63)] = val;
            }
        }
    } else {
#pragma unroll
        for (int j = 0; j < 2; ++j) {
            int s = n0 + w * 32 + j * 16 + l16;
#pragma unroll
            for (int i = 0; i < 4; ++i) {
                int mbase = m0 - 1024 + i * 16 + quad * 4;
#pragma unroll
                for (int r = 0; r < 4; ++r) {
                    int mm = mbase + r;
                    V[((size_t)(b * 512 + mm)) * SEQ + s] = f2bf(acc[i][j][r] + bv[mm]);
                }
            }
        }
    }
}

// ---------------- flash attention partial (split-K x4), 192-q blocks (3 groups), dbuf K/V
__global__ __launch_bounds__(256, 3) void attn_partial(
        const u16* __restrict__ Q,    // [16][2304][64] (pre-scaled by QSCALE)
        const u16* __restrict__ K,    // [16][2304][64]
        const u16* __restrict__ Vt,   // [B][512][2304]
        u16* __restrict__ Opart,      // [4*16][2304][64] chunk-normalized bf16
        float* __restrict__ Lpart) {  // [4*16][2304]
    __shared__ __align__(16) u16 sm[2 * 8192];      // 32 KB: [buf][Ks|Vs], each 64x64
    const int pair = blockIdx.x & 15, qt = blockIdx.x >> 4;   // qt 0..11 (192-q tiles)
    const int c = blockIdx.y;
    const int b = pair >> 3, h = pair & 7;
    const int t = threadIdx.x, lane = t & 63, w = t >> 6;
    const int l16 = lane & 15, quad = lane >> 4;
    const int x7 = l16 & 7;
    const int srow = t >> 3;
    const int scol = (t & 7) * 8;
    const int scol_sw = ((t & 7) ^ (srow & 7)) * 8;
    const int kinv0 = kperm_inv(srow), kinv1 = kperm_inv(32 + srow);
    const int cA = (quad ^ x7) * 8;        // swizzled chunk for logical chunk quad
    const int cB = (quad ^ x7 ^ 4) * 8;    // swizzled chunk for logical chunk quad+4

    // Q fragments for three q-groups (B-frag: n=q, k=d)
    const u16* Qg = Q + ((size_t)pair * SEQ + qt * 192) * 64;
    const int rA = w * 16 + l16;
    short8 qf[3][2];
#pragma unroll
    for (int G = 0; G < 3; ++G) {
        qf[G][0] = *(const short8*)&Qg[(size_t)(G * 64 + rA) * 64 + quad * 8];
        qf[G][1] = *(const short8*)&Qg[(size_t)(G * 64 + rA) * 64 + 32 + quad * 8];
    }

    const u16* Kg = K  + ((size_t)pair * SEQ + c * 576) * 64;
    const u16* Vg = Vt + ((size_t)(b * 512 + h * 64)) * SEQ + c * 576;

    float lacc[3] = {0.f, 0.f, 0.f};
    f32x4 o[3][4] = {};

    // preload kt=0 into buf 0
    {
        u16* Ks = sm; u16* Vs = sm + 4096;
        cp16(&Kg[(size_t)kinv0 * 64 + scol_sw], &Ks[srow * 64 + scol]);
        cp16(&Kg[(size_t)kinv1 * 64 + scol_sw], &Ks[(32 + srow) * 64 + scol]);
        cp16(&Vg[(size_t)srow * SEQ + scol_sw],        &Vs[srow * 64 + scol]);
        cp16(&Vg[(size_t)(32 + srow) * SEQ + scol_sw], &Vs[(32 + srow) * 64 + scol]);
    }
    for (int kt = 0; kt < 9; ++kt) {
        const int pb = kt & 1;
        const u16* Ks = sm + pb * 8192;
        const u16* Vs = Ks + 4096;
        __syncthreads();                              // buf pb ready
        if (kt < 8) {                                 // prefetch kt+1 into buf pb^1
            u16* Kn = sm + (pb ^ 1) * 8192;
            u16* Vn = Kn + 4096;
            cp16(&Kg[(size_t)((kt + 1) * 64 + kinv0) * 64 + scol_sw], &Kn[srow * 64 + scol]);
            cp16(&Kg[(size_t)((kt + 1) * 64 + kinv1) * 64 + scol_sw], &Kn[(32 + srow) * 64 + scol]);
            cp16(&Vg[(size_t)srow * SEQ + (kt + 1) * 64 + scol_sw],        &Vn[srow * 64 + scol]);
            cp16(&Vg[(size_t)(32 + srow) * SEQ + (kt + 1) * 64 + scol_sw], &Vn[(32 + srow) * 64 + scol]);
        }
        // S^T = K Q^T : rows = ki (kperm'd), cols = q; each kf read feeds 3 MFMAs
        f32x4 sacc[3][4];
#pragma unroll
        for (int j = 0; j < 4; ++j) {
            short8 kf0 = *(const short8*)&Ks[(j * 16 + l16) * 64 + cA];
            short8 kf1 = *(const short8*)&Ks[(j * 16 + l16) * 64 + cB];
#pragma unroll
            for (int G = 0; G < 3; ++G) {
                f32x4 z = {0.f, 0.f, 0.f, 0.f};
                z = mfma16(kf0, qf[G][0], z);
                sacc[G][j] = mfma16(kf1, qf[G][1], z);
            }
        }
        // fixed-max softmax; pack P to bf16 immediately (frees fp32 p regs)
        u32 pk[3][8];
#pragma unroll
        for (int G = 0; G < 3; ++G)
#pragma unroll
            for (int j = 0; j < 4; ++j) {
                float e0 = __builtin_amdgcn_exp2f(sacc[G][j][0]);
                float e1 = __builtin_amdgcn_exp2f(sacc[G][j][1]);
                float e2 = __builtin_amdgcn_exp2f(sacc[G][j][2]);
                float e3 = __builtin_amdgcn_exp2f(sacc[G][j][3]);
                lacc[G] += (e0 + e1) + (e2 + e3);
                pk[G][2 * j]     = pkbf(e0, e1);
                pk[G][2 * j + 1] = pkbf(e2, e3);
            }
        // PV: P already in B-frag order thanks to kperm; each vf read feeds 3 MFMAs
#pragma unroll
        for (int g = 0; g < 2; ++g) {
            const int cg = g ? cB : cA;
#pragma unroll
            for (int i = 0; i < 4; ++i) {
                short8 vf = *(const short8*)&Vs[(i * 16 + l16) * 64 + cg];
#pragma unroll
                for (int G = 0; G < 3; ++G) {
                    short8 pf;
                    u32* pw = (u32*)&pf;
                    pw[0] = pk[G][4 * g + 0];
                    pw[1] = pk[G][4 * g + 1];
                    pw[2] = pk[G][4 * g + 2];
                    pw[3] = pk[G][4 * g + 3];
                    o[G][i] = mfma16(vf, pf, o[G][i]);
                }
            }
        }
    }
    // reduce l across quads (lane's q = l16 within group)
    float linv[3];
#pragma unroll
    for (int G = 0; G < 3; ++G) {
        float lr = lacc[G];
        lr += __shfl_xor(lr, 16);
        lr += __shfl_xor(lr, 32);
        if (quad == 0) Lpart[((size_t)(c * 16 + pair)) * SEQ + qt * 192 + G * 64 + rA] = lr;
        linv[G] = 1.0f / lr;
    }
    const size_t orow = ((size_t)(c * 16 + pair)) * SEQ + qt * 192;

    // single merged bounce: 192 rows x 72 stride in the (now free) dbuf LDS
    __syncthreads();
#pragma unroll
    for (int G = 0; G < 3; ++G)
#pragma unroll
        for (int i = 0; i < 4; ++i) {
            uint2 pkv;
            pkv.x = pkbf(o[G][i][0] * linv[G], o[G][i][1] * linv[G]);
            pkv.y = pkbf(o[G][i][2] * linv[G], o[G][i][3] * linv[G]);
            *(uint2*)&sm[(G * 64 + rA) * 72 + i * 16 + quad * 4] = pkv;
        }
    __syncthreads();
#pragma unroll
    for (int it = 0; it < 6; ++it) {
        int v = it * 256 + t;
        int row = v >> 3, col = (v & 7) * 8;
        *(uint4*)&Opart[(orow + row) * 64 + col] = *(const uint4*)&sm[row * 72 + col];
    }
}

// ---------------- combine split-K partials -> At [B][2304][512] bf16
__global__ __launch_bounds__(256) void attn_combine(
        const u16* __restrict__ Opart, const float* __restrict__ Lpart,
        u16* __restrict__ At) {
    const int bid = blockIdx.x;
    const int pair = bid / 144, sb = bid % 144;
    const int tid = threadIdx.x;
    const int rl = tid >> 4, dg = tid & 15;
    const int s = sb * 16 + rl;
    const int b = pair >> 3, h = pair & 7;
    float wc[4], L = 0.f;
#pragma unroll
    for (int c = 0; c < 4; ++c) {
        wc[c] = Lpart[(size_t)(c * 16 + pair) * SEQ + s];
        L += wc[c];
    }
    float invL = 1.0f / L;
    float acc[4] = {0.f, 0.f, 0.f, 0.f};
#pragma unroll
    for (int c = 0; c < 4; ++c) {
        ushort4 v = *(const ushort4*)&Opart[((size_t)(c * 16 + pair) * SEQ + s) * 64 + dg * 4];
        acc[0] += wc[c] * bf2f(v.x);
        acc[1] += wc[c] * bf2f(v.y);
        acc[2] += wc[c] * bf2f(v.z);
        acc[3] += wc[c] * bf2f(v.w);
    }
    uint2 outv;
    outv.x = pkbf(acc[0] * invL, acc[1] * invL);
    outv.y = pkbf(acc[2] * invL, acc[3] * invL);
    *(uint2*)&At[((size_t)b * SEQ + s) * ND + h * 64 + dg * 4] = outv;
}

// ---------------- output projection GEMM (NT), 64x64 tiles, dbuf async staging
__global__ __launch_bounds__(256) void gemm_out_kernel(
        const u16* __restrict__ Wob, const u16* __restrict__ At,
        const float* __restrict__ bo, float* __restrict__ out) {
    __shared__ __align__(16) u16 sm[2 * 8192];       // 32 KB: [buf][As|Bs], each 64x64
    const int n0 = blockIdx.x * 64;
    const int m0 = blockIdx.y * 64;
    const int b  = blockIdx.z;
    const int t = threadIdx.x;
    const int lane = t & 63, w = t >> 6;
    const int l16 = lane & 15, quad = lane >> 4;
    const int x7 = l16 & 7;
    const int srow = t >> 3, scol = (t & 7) * 8;
    const int scol_sw = ((t & 7) ^ (srow & 7)) * 8;
    const u16* Ab = At + (size_t)b * SEQ * ND;

    f32x4 acc[4] = {};

    {
        u16* As = sm; u16* Bs = sm + 4096;
#pragma unroll
        for (int it = 0; it < 2; ++it) {
            int r2 = it * 32 + srow;
            cp16(&Wob[(size_t)(m0 + r2) * 512 + scol_sw], &As[r2 * 64 + scol]);
            cp16(&Ab [(size_t)(n0 + r2) * 512 + scol_sw], &Bs[r2 * 64 + scol]);
        }
    }
    for (int kb = 0; kb < 512; kb += 64) {
        const int pb = (kb >> 6) & 1;
        const u16* As = sm + pb * 8192;
        const u16* Bs = As + 4096;
        __syncthreads();
        if (kb + 64 < 512) {
            u16* An = sm + (pb ^ 1) * 8192;
            u16* Bn = An + 4096;
#pragma unroll
            for (int it = 0; it < 2; ++it) {
                int r2 = it * 32 + srow;
                cp16(&Wob[(size_t)(m0 + r2) * 512 + kb + 64 + scol_sw], &An[r2 * 64 + scol]);
                cp16(&Ab [(size_t)(n0 + r2) * 512 + kb + 64 + scol_sw], &Bn[r2 * 64 + scol]);
            }
        }
#pragma unroll
        for (int kk = 0; kk < 2; ++kk) {
            const int co = ((kk * 4 + quad) ^ x7) * 8;
            short8 af[4];
#pragma unroll
            for (int i = 0; i < 4; ++i)
                af[i] = *(const short8*)&As[(i * 16 + l16) * 64 + co];
            short8 bfr = *(const short8*)&Bs[(w * 16 + l16) * 64 + co];
#pragma unroll
            for (int i = 0; i < 4; ++i)
                acc[i] = mfma16(af[i], bfr, acc[i]);
        }
    }
#pragma unroll
    for (int i = 0; i < 4; ++i) {
        int cbase = m0 + i * 16 + quad * 4;
        int s = n0 + w * 16 + l16;
#pragma unroll
        for (int r = 0; r < 4; ++r) {
            int cc = cbase + r;
            out[((size_t)(b * 512 + cc)) * SEQ + s] = acc[i][r] + bo[cc];
        }
    }
}

extern "C" void kernel_launch(void* const* d_in, const int* in_sizes, int n_in,
                              void* d_out, int out_size, void* d_ws, size_t ws_size,
                              hipStream_t stream) {
    const float* H  = (const float*)d_in[0];
    const float* Wq = (const float*)d_in[1];
    const float* bq = (const float*)d_in[2];
    const float* Wk = (const float*)d_in[3];
    const float* bk = (const float*)d_in[4];
    const float* Wv = (const float*)d_in[5];
    const float* bv = (const float*)d_in[6];
    const float* Wo = (const float*)d_in[7];
    const float* bo = (const float*)d_in[8];
    float* out = (float*)d_out;

    u16* ws    = (u16*)d_ws;
    u16* Wqkv  = ws;                                  // 1536*512
    u16* Wob   = Wqkv  + 1536 * 512;                  // 512*512
    u16* Xbf   = Wob   + 512 * 512;                   // 2*2304*512
    u16* Qb    = Xbf   + 2 * SEQ * CDIM;              // 16*2304*64
    u16* Kb    = Qb    + 2 * SEQ * ND;
    u16* Vb    = Kb    + 2 * SEQ * ND;
    u16* At    = Vb    + 2 * SEQ * ND;
    u16* Opart = At    + 2 * SEQ * ND;                // 64*2304*64
    float* Lpart = (float*)(Opart + 4 * 16 * SEQ * 64);

    prep_kernel<<<6400, 256, 0, stream>>>(H, Wq, Wk, Wv, Wo, Wqkv, Wob, Xbf);
    gemm_qkv_kernel<<<dim3(18, 24, 2), 256, 0, stream>>>(Wqkv, Xbf, bq, bk, bv, Qb, Kb, Vb);
    attn_partial<<<dim3(192, 4), 256, 0, stream>>>(Qb, Kb, Vb, Opart, Lpart);
    attn_combine<<<2304, 256, 0, stream>>>(Opart, Lpart, At);
    gemm_out_kernel<<<dim3(36, 8, 2), 256, 0, stream>>>(Wob, At, bo, out);
}